// Round 7
// baseline (548.171 us; speedup 1.0000x reference)
//
#include <hip/hip_runtime.h>
#include <math.h>

// Sizes (fixed for this problem)
#define NB   16
#define NCIN 512
#define NL   1024
#define NCOUT 1024
#define NK   5
#define NDW  512
#define NHW  196
#define NP   208   // HW padded to 13 n-tiles of 16
#define NPK  224   // HW padded to 7 k-chunks of 32
#define NLG  1028  // NL + 4 zero guard rows at the front of each batch (for conv taps)

typedef unsigned short ushort_t;
typedef unsigned int uint_t;
typedef __attribute__((ext_vector_type(8))) short bf16x8;
typedef __attribute__((ext_vector_type(4))) float f32x4;

static __device__ __forceinline__ ushort_t f2bf(float f) {
  uint_t u = __builtin_bit_cast(uint_t, f);
  u += 0x7fff + ((u >> 16) & 1);  // round-to-nearest-even
  return (ushort_t)(u >> 16);
}
static __device__ __forceinline__ float bf2f(ushort_t u) {
  uint_t v = ((uint_t)u) << 16;
  return __builtin_bit_cast(float, v);
}

// raw barrier / counted waits (avoid __syncthreads' vmcnt(0) drain)
#define BARM()     asm volatile("s_barrier" ::: "memory")
#define WAITVM8()  asm volatile("s_waitcnt vmcnt(8)" ::: "memory")
#define WAITVM0()  asm volatile("s_waitcnt vmcnt(0)" ::: "memory")
#define WAITLGKM0() asm volatile("s_waitcnt lgkmcnt(0)" ::: "memory")

static __device__ __forceinline__ void gld16(const ushort_t* g, ushort_t* l) {
  __builtin_amdgcn_global_load_lds(
      (const __attribute__((address_space(1))) unsigned int*)g,
      (__attribute__((address_space(3))) unsigned int*)l, 16, 0, 0);
}

// ---------------------------------------------------------------------------
// K1: weight norm -> permuted bf16 weights (conv kernel's interleaved order).
// ---------------------------------------------------------------------------
__global__ __launch_bounds__(256) void wnorm_kernel(
    const float* __restrict__ v, const float* __restrict__ g,
    ushort_t* __restrict__ wperm) {
  const int o = blockIdx.x;
  const float* vr = v + (size_t)o * (NCIN * NK);
  float s = 0.f;
  for (int j = threadIdx.x; j < NCIN * NK; j += 256) {
    float t = vr[j];
    s += t * t;
  }
  for (int off = 32; off; off >>= 1) s += __shfl_down(s, off, 64);
  __shared__ float red[4];
  __shared__ float scale_s;
  const int wid = threadIdx.x >> 6;
  if ((threadIdx.x & 63) == 0) red[wid] = s;
  __syncthreads();
  if (threadIdx.x == 0) {
    float tot = red[0] + red[1] + red[2] + red[3];
    scale_s = g[o] / sqrtf(tot);
  }
  __syncthreads();
  const float scale = scale_s;
  const int isB = (o >= NDW) ? 1 : 0;
  const int c = o - isB * NDW;
  const int j = (c >> 5) * 64 + isB * 32 + (c & 31);
#pragma unroll
  for (int dk = 0; dk < NK; ++dk) {
    for (int ci = threadIdx.x; ci < NCIN; ci += 256) {
      wperm[((size_t)dk * NCOUT + j) * NCIN + ci] = f2bf(vr[ci * NK + dk] * scale);
    }
  }
}

// ---------------------------------------------------------------------------
// K2a: transpose + bf16 convert:  xT[b][l+4][ci] = bf16(x[b][ci][l])
// ---------------------------------------------------------------------------
__global__ __launch_bounds__(256) void xpose_kernel(
    const float* __restrict__ x, ushort_t* __restrict__ xT) {
  const int b = blockIdx.z;
  const int ci0 = blockIdx.y * 64;
  const int l0 = blockIdx.x * 64;
  const int tid = threadIdx.x;
  __shared__ float t[64][65];
  const float* xb = x + ((size_t)b * NCIN + ci0) * NL + l0;
#pragma unroll
  for (int r = 0; r < 4; ++r) {
    int row = r * 16 + (tid >> 4);
    int col = (tid & 15) * 4;
    float4 v = *(const float4*)&xb[(size_t)row * NL + col];
    t[row][col + 0] = v.x; t[row][col + 1] = v.y;
    t[row][col + 2] = v.z; t[row][col + 3] = v.w;
  }
  __syncthreads();
  ushort_t* xo = xT + ((size_t)b * NLG + l0 + 4) * NCIN + ci0;
#pragma unroll
  for (int r = 0; r < 4; ++r) {
    int lrow = r * 16 + (tid >> 4);
    int cic = (tid & 15) * 4;
    ushort4 o4;
    o4.x = f2bf(t[cic + 0][lrow]);
    o4.y = f2bf(t[cic + 1][lrow]);
    o4.z = f2bf(t[cic + 2][lrow]);
    o4.w = f2bf(t[cic + 3][lrow]);
    *(ushort4*)&xo[(size_t)lrow * NCIN + cic] = o4;
  }
  // zero the 4 guard rows for this (b, ci-slice)
  if (blockIdx.x == 0) {
    for (int i = tid; i < 4 * 64; i += 256) {
      int rr = i >> 6, cc = i & 63;
      xT[((size_t)b * NLG + rr) * NCIN + ci0 + cc] = 0;
    }
  }
}

// ---------------------------------------------------------------------------
// K-prep: fc1_w / fc2_w -> bf16
// ---------------------------------------------------------------------------
__global__ __launch_bounds__(256) void wcvt_kernel(
    const float* __restrict__ w1, const float* __restrict__ w2,
    ushort_t* __restrict__ w1bf, ushort_t* __restrict__ w2bf) {
  const int i = (blockIdx.x * 256 + threadIdx.x) * 4;
  {
    float4 v = *(const float4*)&w1[i];
    ushort4 o; o.x = f2bf(v.x); o.y = f2bf(v.y); o.z = f2bf(v.z); o.w = f2bf(v.w);
    *(ushort4*)&w1bf[i] = o;
  }
  {
    float4 v = *(const float4*)&w2[i];
    ushort4 o; o.x = f2bf(v.x); o.y = f2bf(v.y); o.z = f2bf(v.z); o.w = f2bf(v.w);
    *(ushort4*)&w2bf[i] = o;
  }
}

// ---------------------------------------------------------------------------
// K-prep: feat transforms.
// ---------------------------------------------------------------------------
__global__ __launch_bounds__(256) void ftrans_kernel(
    const float* __restrict__ feat, ushort_t* __restrict__ fThi,
    ushort_t* __restrict__ fTlo, ushort_t* __restrict__ fbf) {
  const int b = blockIdx.y;
  const int a0 = blockIdx.x * 64;
  const int tid = threadIdx.x;
  __shared__ float t[64][200];

  const float* fb_ = feat + ((size_t)b * NDW + a0) * NHW;
#pragma unroll
  for (int pp = 0; pp < 16; ++pp) {
    int row = pp * 4 + (tid >> 6);
#pragma unroll
    for (int cc = 0; cc < 4; ++cc) {
      int col = cc * 64 + (tid & 63);
      if (col < NHW) t[row][col] = fb_[(size_t)row * NHW + col];
    }
  }
  __syncthreads();

  for (int pp = 0; pp < 13; ++pp) {
    int p = pp * 16 + (tid >> 4);
    int j = (tid & 15) * 4;
    ushort4 hi4, lo4;
#pragma unroll
    for (int k = 0; k < 4; ++k) {
      float v = (p < NHW) ? t[j + k][p] : 0.f;
      ushort_t h = f2bf(v);
      float lof = v - bf2f(h);
      ushort_t l = f2bf(lof);
      ((ushort_t*)&hi4)[k] = h;
      ((ushort_t*)&lo4)[k] = l;
    }
    size_t base = ((size_t)b * NP + p) * NDW + a0 + j;
    *(ushort4*)&fThi[base] = hi4;
    *(ushort4*)&fTlo[base] = lo4;
  }

#pragma unroll
  for (int cc = 0; cc < 4; ++cc) {
    int col = cc * 64 + (tid & 63);
    if (col < NPK) {
#pragma unroll
      for (int rr = 0; rr < 16; ++rr) {
        int al = rr * 4 + (tid >> 6);
        float v = (col < NHW) ? t[al][col] : 0.f;
        fbf[((size_t)b * NDW + a0 + al) * NPK + col] = f2bf(v);
      }
    }
  }
}

// ---------------------------------------------------------------------------
// K2b: conv1d + bias + GLU via bf16 MFMA implicit GEMM — 256x256 phase-split.
// (round-6 verified: race-fixed with lgkmcnt(0) before the overwrite barrier)
// ---------------------------------------------------------------------------
__global__ __launch_bounds__(512, 2) void conv_glu_mfma(
    const ushort_t* __restrict__ xT, const ushort_t* __restrict__ wperm,
    const float* __restrict__ conv_b, ushort_t* __restrict__ hbfT) {
  const int bb = blockIdx.x >> 2;
  const int l0 = (blockIdx.x & 3) * 256;
  const int by = blockIdx.y;
  const int tid = threadIdx.x;
  const int wid = tid >> 6;
  const int lane = tid & 63;
  const int wm = wid >> 2;   // M half (0,1)
  const int wn = wid & 3;    // N quarter (0..3)
  const int quad = lane >> 4;
  const int l16 = lane & 15;
  const int sw = (l16 & 7) << 3;                        // read-side XOR (ushort units)
  const int csrc = ((lane & 7) ^ (lane >> 3)) << 3;     // staging source col (ushort units)

  __shared__ ushort_t sA[2][256][64];
  __shared__ ushort_t sB[2][256][64];

  f32x4 acc[8][4];
#pragma unroll
  for (int mt = 0; mt < 8; ++mt)
#pragma unroll
    for (int nt = 0; nt < 4; ++nt) acc[mt][nt] = (f32x4){0.f, 0.f, 0.f, 0.f};

  const ushort_t* gAbase = xT + (size_t)(bb * NLG + l0) * NCIN;
  const int r0 = wid * 8 + (lane >> 3);
  ushort_t* lA0 = &sA[0][0][0] + (wid * 64 + lane) * 8;
  ushort_t* lB0 = &sB[0][0][0] + (wid * 64 + lane) * 8;

  auto stage = [&](int tt, int s) {
    const int dk = tt >> 3;
    const int ci0 = (tt & 7) << 6;
    const ushort_t* gA = gAbase + (size_t)dk * NCIN + ci0 + csrc;
    const ushort_t* gB = wperm + ((size_t)dk * NCOUT + by * 256) * NCIN + ci0 + csrc;
    ushort_t* lA = lA0 + s * (256 * 64);
    ushort_t* lB = lB0 + s * (256 * 64);
#pragma unroll
    for (int c = 0; c < 4; ++c) {
      gld16(gA + (size_t)(r0 + c * 64) * NCIN, lA + c * 4096);
      gld16(gB + (size_t)(r0 + c * 64) * NCIN, lB + c * 4096);
    }
  };

  stage(0, 0);
  stage(1, 1);
  WAITVM8();
  BARM();

  for (int t = 0; t < 40; ++t) {
    const int s = t & 1;
    bf16x8 af[4][2], bfr[4][2];

    // ---- phase 0: read A(mth=0) + B(nt 0,1); MFMA quadrant (0,0)
#pragma unroll
    for (int mt = 0; mt < 4; ++mt)
#pragma unroll
      for (int ks = 0; ks < 2; ++ks)
        af[mt][ks] = *(const bf16x8*)&sA[s][wm * 128 + mt * 16 + l16]
                                        [(ks * 32 + quad * 8) ^ sw];
#pragma unroll
    for (int nt = 0; nt < 2; ++nt)
#pragma unroll
      for (int ks = 0; ks < 2; ++ks)
        bfr[nt][ks] = *(const bf16x8*)&sB[s][wn * 64 + nt * 16 + l16]
                                         [(ks * 32 + quad * 8) ^ sw];
    BARM();
    __builtin_amdgcn_s_setprio(1);
#pragma unroll
    for (int ks = 0; ks < 2; ++ks)
#pragma unroll
      for (int nt = 0; nt < 2; ++nt)
#pragma unroll
        for (int mt = 0; mt < 4; ++mt)
          acc[mt][nt] = __builtin_amdgcn_mfma_f32_16x16x32_bf16(
              af[mt][ks], bfr[nt][ks], acc[mt][nt], 0, 0, 0);
    __builtin_amdgcn_s_setprio(0);
    BARM();

    // ---- phase 1: read B(nt 2,3); MFMA quadrant (0,1)
#pragma unroll
    for (int nt = 2; nt < 4; ++nt)
#pragma unroll
      for (int ks = 0; ks < 2; ++ks)
        bfr[nt][ks] = *(const bf16x8*)&sB[s][wn * 64 + nt * 16 + l16]
                                         [(ks * 32 + quad * 8) ^ sw];
    BARM();
    __builtin_amdgcn_s_setprio(1);
#pragma unroll
    for (int ks = 0; ks < 2; ++ks)
#pragma unroll
      for (int nt = 2; nt < 4; ++nt)
#pragma unroll
        for (int mt = 0; mt < 4; ++mt)
          acc[mt][nt] = __builtin_amdgcn_mfma_f32_16x16x32_bf16(
              af[mt][ks], bfr[nt][ks], acc[mt][nt], 0, 0, 0);
    __builtin_amdgcn_s_setprio(0);
    BARM();

    // ---- phase 2: read A(mth=1); MFMA quadrant (1,0)
#pragma unroll
    for (int mt = 0; mt < 4; ++mt)
#pragma unroll
      for (int ks = 0; ks < 2; ++ks)
        af[mt][ks] = *(const bf16x8*)&sA[s][wm * 128 + (4 + mt) * 16 + l16]
                                        [(ks * 32 + quad * 8) ^ sw];
    BARM();
    __builtin_amdgcn_s_setprio(1);
#pragma unroll
    for (int ks = 0; ks < 2; ++ks)
#pragma unroll
      for (int nt = 0; nt < 2; ++nt)
#pragma unroll
        for (int mt = 0; mt < 4; ++mt)
          acc[4 + mt][nt] = __builtin_amdgcn_mfma_f32_16x16x32_bf16(
              af[mt][ks], bfr[nt][ks], acc[4 + mt][nt], 0, 0, 0);
    __builtin_amdgcn_s_setprio(0);
    // RACE FIX: drain this wave's LDS reads of slot s BEFORE signalling the
    // barrier that licenses the phase-3 overwrite of slot s.
    WAITLGKM0();
    BARM();

    // ---- phase 3: issue prefetch of tile t+2 into slot s, MFMA (1,1)
    if (t < 38) stage(t + 2, s);
    __builtin_amdgcn_s_setprio(1);
#pragma unroll
    for (int ks = 0; ks < 2; ++ks)
#pragma unroll
      for (int nt = 2; nt < 4; ++nt)
#pragma unroll
        for (int mt = 0; mt < 4; ++mt)
          acc[4 + mt][nt] = __builtin_amdgcn_mfma_f32_16x16x32_bf16(
              af[mt][ks], bfr[nt][ks], acc[4 + mt][nt], 0, 0, 0);
    __builtin_amdgcn_s_setprio(0);

    if (t < 39) {
      if (t < 38) { WAITVM8(); } else { WAITVM0(); }
      BARM();
    }
  }

  // epilogue: GLU, write hbfT[b][l][c] (c < 512)
#pragma unroll
  for (int nt = 0; nt < 2; ++nt) {
    const int c = by * 128 + wn * 32 + nt * 16 + l16;
    const float ba = conv_b[c];
    const float bg = conv_b[c + NDW];
#pragma unroll
    for (int mt = 0; mt < 8; ++mt) {
      const int lg = l0 + wm * 128 + mt * 16 + quad * 4;
      ushort_t* ho = hbfT + ((size_t)bb * NL + lg) * NDW + c;
#pragma unroll
      for (int r = 0; r < 4; ++r) {
        float aa = acc[mt][nt][r] + ba;
        float gg = acc[mt][nt + 2][r] + bg;
        float hv = aa * (1.f / (1.f + __expf(-gg)));
        ho[(size_t)r * NDW] = f2bf(hv);
      }
    }
  }
}

// ---------------------------------------------------------------------------
// K3: FUSED fc1 + score + softmax + ctx  (v3: software-pipelined).
// v2 counters showed grid-capped occupancy (256 blocks = 1/CU regardless of
// LDS) and 90% stall (MfmaUtil 7.4, VALUBusy 5.6, HBM 10.5%). v3 keeps the
// geometry but hides the staging latency via the T14 async-STAGE split:
//  - wS/fh/fl double-buffered in LDS (135.7 KB, fine at 1 block/CU);
//  - chunk k+1's global loads (w1, fThi/fTlo, we, bias) are issued into
//    REGISTERS before chunk k's MFMAs, and written to LDS after the score
//    phase: HBM/L2 latency hides under ~1000 cyc of compute;
//  - phase 2 (ctx) identically pipelined with 32-row fbf chunks.
// All synchronization via __syncthreads (full counter drain) -> race-free:
// buffers written in chunk k were last read in chunk k-1, separated by the
// chunk-(k-1) loop-end barrier.
// __launch_bounds__(256,1): VGPR cap 512 -> the ~240-VGPR peak cannot spill
// (register cost is free at the grid-forced 1 block/CU).
// ---------------------------------------------------------------------------
__global__ __launch_bounds__(256, 1) void attn_fused(
    const ushort_t* __restrict__ hbfT, const ushort_t* __restrict__ w1bf,
    const float* __restrict__ fb1, const float* __restrict__ we,
    const ushort_t* __restrict__ fThi, const ushort_t* __restrict__ fTlo,
    const ushort_t* __restrict__ fbf, float* __restrict__ out_attn,
    ushort_t* __restrict__ ctx_bf) {
  const int b  = blockIdx.y;
  const int l0 = blockIdx.x * 64;
  const int tid = threadIdx.x;
  const int wid = tid >> 6;
  const int lane = tid & 63;
  const int quad = lane >> 4;
  const int l16 = lane & 15;

  // LDS layout (ushort units), total 67840 u = 135.7 KB:
  //   wS[2]  @0      2 x [32][520] = 33280
  //   fh[2]  @33280  2 x [208][36] = 14976
  //   fl[2]  @48256  2 x [208][36] = 14976
  //   qh     @63232  [64][36]      =  2304
  //   ql     @65536  [64][36]      =  2304
  // phase 2 aliases: pa @0 [64][232]=14848; fb[2] @14848 2 x [32][232]=14848
  __shared__ ushort_t smem[67840];
  ushort_t* qh = smem + 63232;
  ushort_t* ql = smem + 65536;
  ushort_t* pa = smem;

  // ---- staging registers (in-flight tile)
  uint4 sfh[4], sfl[4], sw1[8];
  float nwev[2][4], cwev[2][4];
  float nbias[2], cbias[2];

  auto load_stage = [&](int kc) {
    const int a0 = kc * 32;
#pragma unroll
    for (int it = 0; it < 4; ++it) {
      int row = it * 64 + (tid >> 2);
      if (row < NP) {
        size_t fsrc = ((size_t)b * NP + row) * NDW + a0 + (tid & 3) * 8;
        sfh[it] = *(const uint4*)(fThi + fsrc);
        sfl[it] = *(const uint4*)(fTlo + fsrc);
      }
    }
#pragma unroll
    for (int it = 0; it < 8; ++it) {
      int lin = tid + it * 256;
      sw1[it] = *(const uint4*)(w1bf + (size_t)(a0 + (lin >> 6)) * NDW + (lin & 63) * 8);
    }
#pragma unroll
    for (int nt = 0; nt < 2; ++nt) {
      const int a = a0 + nt * 16 + l16;
      nbias[nt] = fb1[a];
#pragma unroll
      for (int r = 0; r < 4; ++r) {
        const int l = l0 + wid * 16 + quad * 4 + r;
        nwev[nt][r] = we[((size_t)b * NL + l) * NDW + a];
      }
    }
  };
  auto store_stage = [&](int s) {
    ushort_t* fhs = smem + 33280 + s * 7488;
    ushort_t* fls = smem + 48256 + s * 7488;
    ushort_t* wSs = smem + s * 16640;
#pragma unroll
    for (int it = 0; it < 4; ++it) {
      int row = it * 64 + (tid >> 2);
      if (row < NP) {
        *(uint4*)&fhs[row * 36 + (tid & 3) * 8] = sfh[it];
        *(uint4*)&fls[row * 36 + (tid & 3) * 8] = sfl[it];
      }
    }
#pragma unroll
    for (int it = 0; it < 8; ++it) {
      int lin = tid + it * 256;
      *(uint4*)&wSs[(lin >> 6) * 520 + (lin & 63) * 8] = sw1[it];
    }
#pragma unroll
    for (int nt = 0; nt < 2; ++nt) {
      cbias[nt] = nbias[nt];
#pragma unroll
      for (int r = 0; r < 4; ++r) cwev[nt][r] = nwev[nt][r];
    }
  };

  // h tile in registers: this wave's 16 l-rows x 512 c as A-fragments.
  uint4 hreg[16];
  {
    const ushort_t* hrow =
        hbfT + ((size_t)b * NL + l0 + wid * 16 + l16) * NDW + quad * 8;
#pragma unroll
    for (int cs = 0; cs < 16; ++cs)
      hreg[cs] = *(const uint4*)(hrow + cs * 32);
  }

  // prologue: stage chunk 0
  load_stage(0);
  store_stage(0);
  __syncthreads();

  f32x4 acc[13];
#pragma unroll
  for (int nt = 0; nt < 13; ++nt) acc[nt] = (f32x4){0.f, 0.f, 0.f, 0.f};

  for (int kc = 0; kc < 16; ++kc) {
    const int cur = kc & 1;
    ushort_t* wSc = smem + cur * 16640;
    ushort_t* fhc = smem + 33280 + cur * 7488;
    ushort_t* flc = smem + 48256 + cur * 7488;

    // A) issue chunk kc+1's global loads (latency hides under B/C/D)
    if (kc < 15) load_stage(kc + 1);

    // B) fc1 chunk: q[wave's 16 l][32 a] over K=512, A from registers
    f32x4 aq[2][2];
    aq[0][0] = aq[0][1] = aq[1][0] = aq[1][1] = (f32x4){0.f, 0.f, 0.f, 0.f};
#pragma unroll
    for (int cs = 0; cs < 16; ++cs) {
      bf16x8 af = __builtin_bit_cast(bf16x8, hreg[cs]);
#pragma unroll
      for (int nt = 0; nt < 2; ++nt) {
        bf16x8 bw = *(const bf16x8*)&wSc[(nt * 16 + l16) * 520 + cs * 32 + quad * 8];
        aq[cs & 1][nt] = __builtin_amdgcn_mfma_f32_16x16x32_bf16(af, bw, aq[cs & 1][nt], 0, 0, 0);
      }
    }
    // C) q epilogue: bias + we, split to bf16 hi/lo via LDS bounce
#pragma unroll
    for (int nt = 0; nt < 2; ++nt) {
#pragma unroll
      for (int r = 0; r < 4; ++r) {
        float qv = aq[0][nt][r] + aq[1][nt][r] + cbias[nt] + cwev[nt][r];
        ushort_t h = f2bf(qv);
        const int row = wid * 16 + quad * 4 + r;
        qh[row * 36 + nt * 16 + l16] = h;
        ql[row * 36 + nt * 16 + l16] = f2bf(qv - bf2f(h));
      }
    }
    __syncthreads();

    // D) score chunk: 3-pass split-bf16 MFMA
    bf16x8 ah = *(const bf16x8*)&qh[(wid * 16 + l16) * 36 + quad * 8];
    bf16x8 al = *(const bf16x8*)&ql[(wid * 16 + l16) * 36 + quad * 8];
#pragma unroll
    for (int nt = 0; nt < 13; ++nt) {
      bf16x8 bh = *(const bf16x8*)&fhc[(nt * 16 + l16) * 36 + quad * 8];
      bf16x8 bl = *(const bf16x8*)&flc[(nt * 16 + l16) * 36 + quad * 8];
      acc[nt] = __builtin_amdgcn_mfma_f32_16x16x32_bf16(ah, bh, acc[nt], 0, 0, 0);
      acc[nt] = __builtin_amdgcn_mfma_f32_16x16x32_bf16(al, bh, acc[nt], 0, 0, 0);
      acc[nt] = __builtin_amdgcn_mfma_f32_16x16x32_bf16(ah, bl, acc[nt], 0, 0, 0);
    }

    // E) write prefetched regs -> buf[cur^1] (last read in chunk kc-1,
    //    separated by that chunk's loop-end barrier -> safe)
    if (kc < 15) store_stage(cur ^ 1);
    __syncthreads();
  }

  // ---- softmax per row; leave normalized attn in acc[][]; write out_attn
  const bool v12 = (l16 < 4);
#pragma unroll
  for (int r = 0; r < 4; ++r) {
    float mx = -1e30f;
#pragma unroll
    for (int nt = 0; nt < 12; ++nt) mx = fmaxf(mx, acc[nt][r]);
    if (v12) mx = fmaxf(mx, acc[12][r]);
#pragma unroll
    for (int off = 1; off < 16; off <<= 1) mx = fmaxf(mx, __shfl_xor(mx, off, 16));
    float ex[13];
    float sum = 0.f;
#pragma unroll
    for (int nt = 0; nt < 12; ++nt) { ex[nt] = __expf(acc[nt][r] - mx); sum += ex[nt]; }
    ex[12] = v12 ? __expf(acc[12][r] - mx) : 0.f;
    sum += ex[12];
#pragma unroll
    for (int off = 1; off < 16; off <<= 1) sum += __shfl_xor(sum, off, 16);
    const float inv = 1.f / sum;
    const int l = l0 + wid * 16 + quad * 4 + r;
    float* ao = out_attn + ((size_t)b * NL + l) * NHW;
#pragma unroll
    for (int nt = 0; nt < 13; ++nt) {
      float av = ex[nt] * inv;
      acc[nt][r] = av;
      int p = nt * 16 + l16;
      if (p < NHW) ao[p] = av;
    }
  }

  __syncthreads();  // all waves done with phase-1 LDS -> safe to alias

  // ---- phase 2: attn -> pa (bf16, padded to 224), then pipelined ctx MFMA
  uint4 sfb[4];
  auto load_fb = [&](int ac) {
#pragma unroll
    for (int it = 0; it < 4; ++it) {
      int lin = tid + it * 256;
      if (lin < 896)
        sfb[it] = *(const uint4*)(fbf +
            ((size_t)b * NDW + ac * 32 + lin / 28) * NPK + (lin % 28) * 8);
    }
  };
  auto store_fb = [&](int s) {
    ushort_t* fbs = smem + 14848 + s * 7424;
#pragma unroll
    for (int it = 0; it < 4; ++it) {
      int lin = tid + it * 256;
      if (lin < 896)
        *(uint4*)&fbs[(lin / 28) * 232 + (lin % 28) * 8] = sfb[it];
    }
  };

#pragma unroll
  for (int r = 0; r < 4; ++r) {
    const int row = wid * 16 + quad * 4 + r;
#pragma unroll
    for (int nt = 0; nt < 13; ++nt) {
      int p = nt * 16 + l16;
      pa[row * 232 + p] = (p < NHW) ? f2bf(acc[nt][r]) : (ushort_t)0;
    }
    pa[row * 232 + 208 + l16] = 0;
  }
  load_fb(0);
  store_fb(0);
  __syncthreads();

  for (int ac = 0; ac < 16; ++ac) {
    const int cur = ac & 1;
    ushort_t* fbc = smem + 14848 + cur * 7424;
    if (ac < 15) load_fb(ac + 1);

    f32x4 ca[2];
    ca[0] = ca[1] = (f32x4){0.f, 0.f, 0.f, 0.f};
#pragma unroll
    for (int ks = 0; ks < 7; ++ks) {
      bf16x8 af = *(const bf16x8*)&pa[(wid * 16 + l16) * 232 + ks * 32 + quad * 8];
#pragma unroll
      for (int nt = 0; nt < 2; ++nt) {
        bf16x8 bv = *(const bf16x8*)&fbc[(nt * 16 + l16) * 232 + ks * 32 + quad * 8];
        ca[nt] = __builtin_amdgcn_mfma_f32_16x16x32_bf16(af, bv, ca[nt], 0, 0, 0);
      }
    }
#pragma unroll
    for (int nt = 0; nt < 2; ++nt) {
      const int a = ac * 32 + nt * 16 + l16;
#pragma unroll
      for (int r = 0; r < 4; ++r) {
        const int l = l0 + wid * 16 + quad * 4 + r;
        ctx_bf[((size_t)b * NL + l) * NDW + a] = f2bf(ca[nt][r]);
      }
    }
    if (ac < 15) store_fb(cur ^ 1);
    __syncthreads();
  }
}

// ---------------------------------------------------------------------------
// K5: fc2 MFMA.  out[c][l] = sum_a w2bf[c][a]*ctx_bf[l][a] + fb2[c] + h + x
// ---------------------------------------------------------------------------
__global__ __launch_bounds__(256, 2) void fc2_mfma(
    const ushort_t* __restrict__ w2bf, const ushort_t* __restrict__ ctx_bf,
    const float* __restrict__ fb2, const ushort_t* __restrict__ hbfT,
    const float* __restrict__ x, float* __restrict__ out0) {
  const int b  = blockIdx.z;
  const int c0 = blockIdx.y * 128;
  const int l0 = blockIdx.x * 128;
  const int tid = threadIdx.x;
  const int wid = tid >> 6;
  const int lane = tid & 63;
  const int wl = wid & 1;   // c sub-tile
  const int wc = wid >> 1;  // l sub-tile
  const int quad = lane >> 4;
  const int l16 = lane & 15;

  __shared__ ushort_t la[128][72];
  __shared__ ushort_t lb[128][72];

  f32x4 acc[4][4];
#pragma unroll
  for (int mt = 0; mt < 4; ++mt)
#pragma unroll
    for (int nt = 0; nt < 4; ++nt) acc[mt][nt] = (f32x4){0.f, 0.f, 0.f, 0.f};

  for (int a0 = 0; a0 < NDW; a0 += 64) {
    __syncthreads();
#pragma unroll
    for (int it = 0; it < 4; ++it) {
      int t = tid + it * 256;
      int r = t >> 3, seg = t & 7;
      *(uint4*)&la[r][seg * 8] = *(const uint4*)(w2bf + (size_t)(c0 + r) * NDW + a0 + seg * 8);
    }
#pragma unroll
    for (int it = 0; it < 4; ++it) {
      int t = tid + it * 256;
      int r = t >> 3, seg = t & 7;
      *(uint4*)&lb[r][seg * 8] =
          *(const uint4*)(ctx_bf + ((size_t)b * NL + l0 + r) * NDW + a0 + seg * 8);
    }
    __syncthreads();
#pragma unroll
    for (int ks = 0; ks < 2; ++ks) {
      bf16x8 af[4];
#pragma unroll
      for (int mt = 0; mt < 4; ++mt)
        af[mt] = *(const bf16x8*)&la[wl * 64 + mt * 16 + l16][ks * 32 + quad * 8];
#pragma unroll
      for (int nt = 0; nt < 4; ++nt) {
        bf16x8 bf = *(const bf16x8*)&lb[wc * 64 + nt * 16 + l16][ks * 32 + quad * 8];
#pragma unroll
        for (int mt = 0; mt < 4; ++mt)
          acc[mt][nt] = __builtin_amdgcn_mfma_f32_16x16x32_bf16(af[mt], bf, acc[mt][nt], 0, 0, 0);
      }
    }
  }

#pragma unroll
  for (int mt = 0; mt < 4; ++mt) {
    const int cb = c0 + wl * 64 + mt * 16 + quad * 4;
    float4 bias4 = *(const float4*)&fb2[cb];
#pragma unroll
    for (int nt = 0; nt < 4; ++nt) {
      const int l = l0 + wc * 64 + nt * 16 + l16;
      ushort4 h4 = *(const ushort4*)&hbfT[((size_t)b * NL + l) * NDW + cb];
      const float bias[4] = {bias4.x, bias4.y, bias4.z, bias4.w};
      const ushort_t hs[4] = {h4.x, h4.y, h4.z, h4.w};
#pragma unroll
      for (int r = 0; r < 4; ++r) {
        size_t idx = ((size_t)b * NDW + cb + r) * NL + l;
        out0[idx] = acc[mt][nt][r] + bias[r] + bf2f(hs[r]) + x[idx];
      }
    }
  }
}

// ---------------------------------------------------------------------------
extern "C" void kernel_launch(void* const* d_in, const int* in_sizes, int n_in,
                              void* d_out, int out_size, void* d_ws, size_t ws_size,
                              hipStream_t stream) {
  const float* x      = (const float*)d_in[0];
  const float* we     = (const float*)d_in[1];
  const float* img    = (const float*)d_in[2];
  const float* conv_v = (const float*)d_in[4];
  const float* conv_g = (const float*)d_in[5];
  const float* conv_b = (const float*)d_in[6];
  const float* fc1_w  = (const float*)d_in[7];
  const float* fc1_b  = (const float*)d_in[8];
  const float* fc2_w  = (const float*)d_in[9];
  const float* fc2_b  = (const float*)d_in[10];

  float* out0     = (float*)d_out;          // (16,512,1024)
  float* out_we   = out0 + 8388608;         // (16,1024,512)
  float* out_img  = out_we + 8388608;       // (16,512,14,14)
  float* out_attn = out_img + 1605632;      // (16,1024,196)

  // Workspace layout (ushort units).
  ushort_t* wsu = (ushort_t*)d_ws;
  ushort_t* wperm = wsu;                    // 2,621,440   [phase A]
  ushort_t* xT    = wsu + 2621440;          // 8,421,376 (16x1028x512) [phase A]
  ushort_t* ctx_b = wsu;                    // 8,388,608   [attn_fused -> fc2; wperm/xT dead]
  ushort_t* hbfT  = wsu + 16777216;         // 8,388,608   [conv -> attn_fused/fc2]
  ushort_t* w1bf  = wsu + 25165824;         // 262,144
  ushort_t* w2bf  = wsu + 25165824 + 262144;  // 262,144
  ushort_t* fThi  = wsu + 25690112;         // 1,703,936
  ushort_t* fTlo  = wsu + 27394048;         // 1,703,936
  ushort_t* fbf   = wsu + 29097984;         // 1,835,008  -> ends 30,932,992

  wnorm_kernel<<<dim3(NCOUT), 256, 0, stream>>>(conv_v, conv_g, wperm);
  xpose_kernel<<<dim3(16, 8, NB), 256, 0, stream>>>(x, xT);
  wcvt_kernel<<<dim3(256), 256, 0, stream>>>(fc1_w, fc2_w, w1bf, w2bf);
  ftrans_kernel<<<dim3(8, NB), 256, 0, stream>>>(img, fThi, fTlo, fbf);

  conv_glu_mfma<<<dim3(64, 4), 512, 0, stream>>>(xT, wperm, conv_b, hbfT);
  attn_fused<<<dim3(16, NB), 256, 0, stream>>>(hbfT, w1bf, fc1_b, we,
                                               fThi, fTlo, fbf, out_attn, ctx_b);
  fc2_mfma<<<dim3(8, 4, NB), 256, 0, stream>>>(w2bf, ctx_b, fc2_b, hbfT, x, out0);

  hipMemcpyAsync(out_we, we, (size_t)8388608 * sizeof(float),
                 hipMemcpyDeviceToDevice, stream);
  hipMemcpyAsync(out_img, img, (size_t)1605632 * sizeof(float),
                 hipMemcpyDeviceToDevice, stream);
}

// Round 8
// 391.637 us; speedup vs baseline: 1.3997x; 1.3997x over previous
//
#include <hip/hip_runtime.h>
#include <math.h>

// Sizes (fixed for this problem)
#define NB   16
#define NCIN 512
#define NL   1024
#define NCOUT 1024
#define NK   5
#define NDW  512
#define NHW  196
#define NP   208   // HW padded to 13 n-tiles of 16
#define NPK  224   // HW padded to 7 k-chunks of 32
#define NLG  1028  // NL + 4 zero guard rows at the front of each batch (for conv taps)

typedef unsigned short ushort_t;
typedef unsigned int uint_t;
typedef __attribute__((ext_vector_type(8))) short bf16x8;
typedef __attribute__((ext_vector_type(4))) float f32x4;

static __device__ __forceinline__ ushort_t f2bf(float f) {
  uint_t u = __builtin_bit_cast(uint_t, f);
  u += 0x7fff + ((u >> 16) & 1);  // round-to-nearest-even
  return (ushort_t)(u >> 16);
}
static __device__ __forceinline__ float bf2f(ushort_t u) {
  uint_t v = ((uint_t)u) << 16;
  return __builtin_bit_cast(float, v);
}

// raw barrier / counted waits (avoid __syncthreads' vmcnt(0) drain)
#define BARM()      asm volatile("s_barrier" ::: "memory")
#define WAITVM8()   asm volatile("s_waitcnt vmcnt(8)" ::: "memory")
#define WAITVM0()   asm volatile("s_waitcnt vmcnt(0)" ::: "memory")
#define WAITLGKM0() asm volatile("s_waitcnt lgkmcnt(0)" ::: "memory")

static __device__ __forceinline__ void gld16(const ushort_t* g, ushort_t* l) {
  __builtin_amdgcn_global_load_lds(
      (const __attribute__((address_space(1))) unsigned int*)g,
      (__attribute__((address_space(3))) unsigned int*)l, 16, 0, 0);
}

// ---------------------------------------------------------------------------
// K1: weight norm -> permuted bf16 weights (conv kernel's interleaved order).
// ---------------------------------------------------------------------------
__global__ __launch_bounds__(256) void wnorm_kernel(
    const float* __restrict__ v, const float* __restrict__ g,
    ushort_t* __restrict__ wperm) {
  const int o = blockIdx.x;
  const float* vr = v + (size_t)o * (NCIN * NK);
  float s = 0.f;
  for (int j = threadIdx.x; j < NCIN * NK; j += 256) {
    float t = vr[j];
    s += t * t;
  }
  for (int off = 32; off; off >>= 1) s += __shfl_down(s, off, 64);
  __shared__ float red[4];
  __shared__ float scale_s;
  const int wid = threadIdx.x >> 6;
  if ((threadIdx.x & 63) == 0) red[wid] = s;
  __syncthreads();
  if (threadIdx.x == 0) {
    float tot = red[0] + red[1] + red[2] + red[3];
    scale_s = g[o] / sqrtf(tot);
  }
  __syncthreads();
  const float scale = scale_s;
  const int isB = (o >= NDW) ? 1 : 0;
  const int c = o - isB * NDW;
  const int j = (c >> 5) * 64 + isB * 32 + (c & 31);
#pragma unroll
  for (int dk = 0; dk < NK; ++dk) {
    for (int ci = threadIdx.x; ci < NCIN; ci += 256) {
      wperm[((size_t)dk * NCOUT + j) * NCIN + ci] = f2bf(vr[ci * NK + dk] * scale);
    }
  }
}

// ---------------------------------------------------------------------------
// K2a: transpose + bf16 convert:  xT[b][l+4][ci] = bf16(x[b][ci][l])
// ---------------------------------------------------------------------------
__global__ __launch_bounds__(256) void xpose_kernel(
    const float* __restrict__ x, ushort_t* __restrict__ xT) {
  const int b = blockIdx.z;
  const int ci0 = blockIdx.y * 64;
  const int l0 = blockIdx.x * 64;
  const int tid = threadIdx.x;
  __shared__ float t[64][65];
  const float* xb = x + ((size_t)b * NCIN + ci0) * NL + l0;
#pragma unroll
  for (int r = 0; r < 4; ++r) {
    int row = r * 16 + (tid >> 4);
    int col = (tid & 15) * 4;
    float4 v = *(const float4*)&xb[(size_t)row * NL + col];
    t[row][col + 0] = v.x; t[row][col + 1] = v.y;
    t[row][col + 2] = v.z; t[row][col + 3] = v.w;
  }
  __syncthreads();
  ushort_t* xo = xT + ((size_t)b * NLG + l0 + 4) * NCIN + ci0;
#pragma unroll
  for (int r = 0; r < 4; ++r) {
    int lrow = r * 16 + (tid >> 4);
    int cic = (tid & 15) * 4;
    ushort4 o4;
    o4.x = f2bf(t[cic + 0][lrow]);
    o4.y = f2bf(t[cic + 1][lrow]);
    o4.z = f2bf(t[cic + 2][lrow]);
    o4.w = f2bf(t[cic + 3][lrow]);
    *(ushort4*)&xo[(size_t)lrow * NCIN + cic] = o4;
  }
  // zero the 4 guard rows for this (b, ci-slice)
  if (blockIdx.x == 0) {
    for (int i = tid; i < 4 * 64; i += 256) {
      int rr = i >> 6, cc = i & 63;
      xT[((size_t)b * NLG + rr) * NCIN + ci0 + cc] = 0;
    }
  }
}

// ---------------------------------------------------------------------------
// K-prep: fc1_w / fc2_w -> bf16
// ---------------------------------------------------------------------------
__global__ __launch_bounds__(256) void wcvt_kernel(
    const float* __restrict__ w1, const float* __restrict__ w2,
    ushort_t* __restrict__ w1bf, ushort_t* __restrict__ w2bf) {
  const int i = (blockIdx.x * 256 + threadIdx.x) * 4;
  {
    float4 v = *(const float4*)&w1[i];
    ushort4 o; o.x = f2bf(v.x); o.y = f2bf(v.y); o.z = f2bf(v.z); o.w = f2bf(v.w);
    *(ushort4*)&w1bf[i] = o;
  }
  {
    float4 v = *(const float4*)&w2[i];
    ushort4 o; o.x = f2bf(v.x); o.y = f2bf(v.y); o.z = f2bf(v.z); o.w = f2bf(v.w);
    *(ushort4*)&w2bf[i] = o;
  }
}

// ---------------------------------------------------------------------------
// K-prep: feat transforms.
// ---------------------------------------------------------------------------
__global__ __launch_bounds__(256) void ftrans_kernel(
    const float* __restrict__ feat, ushort_t* __restrict__ fThi,
    ushort_t* __restrict__ fTlo, ushort_t* __restrict__ fbf) {
  const int b = blockIdx.y;
  const int a0 = blockIdx.x * 64;
  const int tid = threadIdx.x;
  __shared__ float t[64][200];

  const float* fb_ = feat + ((size_t)b * NDW + a0) * NHW;
#pragma unroll
  for (int pp = 0; pp < 16; ++pp) {
    int row = pp * 4 + (tid >> 6);
#pragma unroll
    for (int cc = 0; cc < 4; ++cc) {
      int col = cc * 64 + (tid & 63);
      if (col < NHW) t[row][col] = fb_[(size_t)row * NHW + col];
    }
  }
  __syncthreads();

  for (int pp = 0; pp < 13; ++pp) {
    int p = pp * 16 + (tid >> 4);
    int j = (tid & 15) * 4;
    ushort4 hi4, lo4;
#pragma unroll
    for (int k = 0; k < 4; ++k) {
      float v = (p < NHW) ? t[j + k][p] : 0.f;
      ushort_t h = f2bf(v);
      float lof = v - bf2f(h);
      ushort_t l = f2bf(lof);
      ((ushort_t*)&hi4)[k] = h;
      ((ushort_t*)&lo4)[k] = l;
    }
    size_t base = ((size_t)b * NP + p) * NDW + a0 + j;
    *(ushort4*)&fThi[base] = hi4;
    *(ushort4*)&fTlo[base] = lo4;
  }

#pragma unroll
  for (int cc = 0; cc < 4; ++cc) {
    int col = cc * 64 + (tid & 63);
    if (col < NPK) {
#pragma unroll
      for (int rr = 0; rr < 16; ++rr) {
        int al = rr * 4 + (tid >> 6);
        float v = (col < NHW) ? t[al][col] : 0.f;
        fbf[((size_t)b * NDW + a0 + al) * NPK + col] = f2bf(v);
      }
    }
  }
}

// ---------------------------------------------------------------------------
// K2b: conv1d + bias + GLU via bf16 MFMA implicit GEMM — 256x256 phase-split.
// (round-6 verified: race-fixed with lgkmcnt(0) before the overwrite barrier)
// ---------------------------------------------------------------------------
__global__ __launch_bounds__(512, 2) void conv_glu_mfma(
    const ushort_t* __restrict__ xT, const ushort_t* __restrict__ wperm,
    const float* __restrict__ conv_b, ushort_t* __restrict__ hbfT) {
  const int bb = blockIdx.x >> 2;
  const int l0 = (blockIdx.x & 3) * 256;
  const int by = blockIdx.y;
  const int tid = threadIdx.x;
  const int wid = tid >> 6;
  const int lane = tid & 63;
  const int wm = wid >> 2;   // M half (0,1)
  const int wn = wid & 3;    // N quarter (0..3)
  const int quad = lane >> 4;
  const int l16 = lane & 15;
  const int sw = (l16 & 7) << 3;                        // read-side XOR (ushort units)
  const int csrc = ((lane & 7) ^ (lane >> 3)) << 3;     // staging source col (ushort units)

  __shared__ ushort_t sA[2][256][64];
  __shared__ ushort_t sB[2][256][64];

  f32x4 acc[8][4];
#pragma unroll
  for (int mt = 0; mt < 8; ++mt)
#pragma unroll
    for (int nt = 0; nt < 4; ++nt) acc[mt][nt] = (f32x4){0.f, 0.f, 0.f, 0.f};

  const ushort_t* gAbase = xT + (size_t)(bb * NLG + l0) * NCIN;
  const int r0 = wid * 8 + (lane >> 3);
  ushort_t* lA0 = &sA[0][0][0] + (wid * 64 + lane) * 8;
  ushort_t* lB0 = &sB[0][0][0] + (wid * 64 + lane) * 8;

  auto stage = [&](int tt, int s) {
    const int dk = tt >> 3;
    const int ci0 = (tt & 7) << 6;
    const ushort_t* gA = gAbase + (size_t)dk * NCIN + ci0 + csrc;
    const ushort_t* gB = wperm + ((size_t)dk * NCOUT + by * 256) * NCIN + ci0 + csrc;
    ushort_t* lA = lA0 + s * (256 * 64);
    ushort_t* lB = lB0 + s * (256 * 64);
#pragma unroll
    for (int c = 0; c < 4; ++c) {
      gld16(gA + (size_t)(r0 + c * 64) * NCIN, lA + c * 4096);
      gld16(gB + (size_t)(r0 + c * 64) * NCIN, lB + c * 4096);
    }
  };

  stage(0, 0);
  stage(1, 1);
  WAITVM8();
  BARM();

  for (int t = 0; t < 40; ++t) {
    const int s = t & 1;
    bf16x8 af[4][2], bfr[4][2];

    // ---- phase 0: read A(mth=0) + B(nt 0,1); MFMA quadrant (0,0)
#pragma unroll
    for (int mt = 0; mt < 4; ++mt)
#pragma unroll
      for (int ks = 0; ks < 2; ++ks)
        af[mt][ks] = *(const bf16x8*)&sA[s][wm * 128 + mt * 16 + l16]
                                        [(ks * 32 + quad * 8) ^ sw];
#pragma unroll
    for (int nt = 0; nt < 2; ++nt)
#pragma unroll
      for (int ks = 0; ks < 2; ++ks)
        bfr[nt][ks] = *(const bf16x8*)&sB[s][wn * 64 + nt * 16 + l16]
                                         [(ks * 32 + quad * 8) ^ sw];
    BARM();
    __builtin_amdgcn_s_setprio(1);
#pragma unroll
    for (int ks = 0; ks < 2; ++ks)
#pragma unroll
      for (int nt = 0; nt < 2; ++nt)
#pragma unroll
        for (int mt = 0; mt < 4; ++mt)
          acc[mt][nt] = __builtin_amdgcn_mfma_f32_16x16x32_bf16(
              af[mt][ks], bfr[nt][ks], acc[mt][nt], 0, 0, 0);
    __builtin_amdgcn_s_setprio(0);
    BARM();

    // ---- phase 1: read B(nt 2,3); MFMA quadrant (0,1)
#pragma unroll
    for (int nt = 2; nt < 4; ++nt)
#pragma unroll
      for (int ks = 0; ks < 2; ++ks)
        bfr[nt][ks] = *(const bf16x8*)&sB[s][wn * 64 + nt * 16 + l16]
                                         [(ks * 32 + quad * 8) ^ sw];
    BARM();
    __builtin_amdgcn_s_setprio(1);
#pragma unroll
    for (int ks = 0; ks < 2; ++ks)
#pragma unroll
      for (int nt = 2; nt < 4; ++nt)
#pragma unroll
        for (int mt = 0; mt < 4; ++mt)
          acc[mt][nt] = __builtin_amdgcn_mfma_f32_16x16x32_bf16(
              af[mt][ks], bfr[nt][ks], acc[mt][nt], 0, 0, 0);
    __builtin_amdgcn_s_setprio(0);
    BARM();

    // ---- phase 2: read A(mth=1); MFMA quadrant (1,0)
#pragma unroll
    for (int mt = 0; mt < 4; ++mt)
#pragma unroll
      for (int ks = 0; ks < 2; ++ks)
        af[mt][ks] = *(const bf16x8*)&sA[s][wm * 128 + (4 + mt) * 16 + l16]
                                        [(ks * 32 + quad * 8) ^ sw];
    BARM();
    __builtin_amdgcn_s_setprio(1);
#pragma unroll
    for (int ks = 0; ks < 2; ++ks)
#pragma unroll
      for (int nt = 0; nt < 2; ++nt)
#pragma unroll
        for (int mt = 0; mt < 4; ++mt)
          acc[4 + mt][nt] = __builtin_amdgcn_mfma_f32_16x16x32_bf16(
              af[mt][ks], bfr[nt][ks], acc[4 + mt][nt], 0, 0, 0);
    __builtin_amdgcn_s_setprio(0);
    // RACE FIX: drain this wave's LDS reads of slot s BEFORE signalling the
    // barrier that licenses the phase-3 overwrite of slot s.
    WAITLGKM0();
    BARM();

    // ---- phase 3: issue prefetch of tile t+2 into slot s, MFMA (1,1)
    if (t < 38) stage(t + 2, s);
    __builtin_amdgcn_s_setprio(1);
#pragma unroll
    for (int ks = 0; ks < 2; ++ks)
#pragma unroll
      for (int nt = 2; nt < 4; ++nt)
#pragma unroll
        for (int mt = 0; mt < 4; ++mt)
          acc[4 + mt][nt] = __builtin_amdgcn_mfma_f32_16x16x32_bf16(
              af[mt][ks], bfr[nt][ks], acc[4 + mt][nt], 0, 0, 0);
    __builtin_amdgcn_s_setprio(0);

    if (t < 39) {
      if (t < 38) { WAITVM8(); } else { WAITVM0(); }
      BARM();
    }
  }

  // epilogue: GLU, write hbfT[b][l][c] (c < 512)
#pragma unroll
  for (int nt = 0; nt < 2; ++nt) {
    const int c = by * 128 + wn * 32 + nt * 16 + l16;
    const float ba = conv_b[c];
    const float bg = conv_b[c + NDW];
#pragma unroll
    for (int mt = 0; mt < 8; ++mt) {
      const int lg = l0 + wm * 128 + mt * 16 + quad * 4;
      ushort_t* ho = hbfT + ((size_t)bb * NL + lg) * NDW + c;
#pragma unroll
      for (int r = 0; r < 4; ++r) {
        float aa = acc[mt][nt][r] + ba;
        float gg = acc[mt][nt + 2][r] + bg;
        float hv = aa * (1.f / (1.f + __expf(-gg)));
        ho[(size_t)r * NDW] = f2bf(hv);
      }
    }
  }
}

// ---------------------------------------------------------------------------
// K3: FUSED fc1 + score + softmax + ctx  (v4: global_load_lds pipeline).
// v3 failed: register staging spilled to scratch (WRITE_SIZE 29->154 MB).
// v4 stages directly global->LDS with gld16 (zero staging registers):
//  - double-buffered LINEAR LDS layouts + both-sides XOR swizzles (rule 21):
//      wS [32][512], col ^= (row&7)<<3          (read: 2-way, free)
//      fh/fl [208][32], col ^= ((row+(row>>2))&3)<<3   (read: 2-way, free)
//      fbf [32][224], same swizzle              (read: 2-way, free)
//  - chunk k+1 staged (58 gld16 block-wide) before chunk k's MFMAs;
//    chunk-end lgkmcnt(0)+vmcnt(0)+s_barrier drains ~600cyc after issue.
//  - qh/ql are wave-private -> mid-chunk needs only lgkmcnt(0), NO barrier.
// ---------------------------------------------------------------------------
__global__ __launch_bounds__(256, 2) void attn_fused(
    const ushort_t* __restrict__ hbfT, const ushort_t* __restrict__ w1bf,
    const float* __restrict__ fb1, const float* __restrict__ we,
    const ushort_t* __restrict__ fThi, const ushort_t* __restrict__ fTlo,
    const ushort_t* __restrict__ fbf, float* __restrict__ out_attn,
    ushort_t* __restrict__ ctx_bf) {
  const int b  = blockIdx.y;
  const int l0 = blockIdx.x * 64;
  const int tid = threadIdx.x;
  const int wid = tid >> 6;
  const int lane = tid & 63;
  const int quad = lane >> 4;
  const int l16 = lane & 15;
  const int s_f = ((l16 & 3) + (l16 >> 2)) & 3;  // fh/fl/fbf read swizzle slot
  const int wmask = (l16 & 7) << 3;              // wS read swizzle (ushort units)

  // LDS layout (ushort units), total 64000 u = 125 KiB:
  //   wS[2] @0     2 x [32][512] = 32768
  //   fh[2] @32768 2 x [208][32] = 13312
  //   fl[2] @46080 2 x [208][32] = 13312
  //   qh    @59392 [64][36] = 2304
  //   ql    @61696 [64][36] = 2304
  // phase 2 aliases: pa @0 [64][232]=14848; fb[2] @14848 2 x [32][224]=14336
  __shared__ ushort_t smem[64000];
  ushort_t* qh = smem + 59392;
  ushort_t* ql = smem + 61696;
  ushort_t* pa = smem;

  // stage chunk kc's w1 + fThi/fTlo slab into LDS buffer s via gld16.
  auto stage1 = [&](int kc, int s) {
    const int a0 = kc * 32;
    ushort_t* wSb = smem + s * 16384;
    ushort_t* fhb = smem + 32768 + s * 6656;
    ushort_t* flb = smem + 46080 + s * 6656;
    // wS: 32 rows x 1024B, one wave-issue per row; wave wid does rows wid+4k.
#pragma unroll
    for (int rr = 0; rr < 8; ++rr) {
      const int r = rr * 4 + wid;
      gld16(w1bf + (size_t)(a0 + r) * NDW + ((lane * 8) ^ ((r & 7) << 3)),
            wSb + r * 512 + lane * 8);
    }
    // fh/fl: 13 issues x 16 rows x 64B each.
#pragma unroll
    for (int ii = 0; ii < 4; ++ii) {
      const int i = ii * 4 + wid;
      if (i < 13) {
        const int row = i * 16 + (lane >> 2);
        const int s4 = (row + (row >> 2)) & 3;
        const size_t gsrc =
            ((size_t)b * NP + row) * NDW + a0 + (((lane & 3) * 8) ^ (s4 << 3));
        gld16(fThi + gsrc, fhb + i * 512 + lane * 8);
        gld16(fTlo + gsrc, flb + i * 512 + lane * 8);
      }
    }
  };

  // h tile in registers: this wave's 16 l-rows x 512 c as A-fragments.
  uint4 hreg[16];
  {
    const ushort_t* hrow =
        hbfT + ((size_t)b * NL + l0 + wid * 16 + l16) * NDW + quad * 8;
#pragma unroll
    for (int cs = 0; cs < 16; ++cs)
      hreg[cs] = *(const uint4*)(hrow + cs * 32);
  }

  stage1(0, 0);
  __syncthreads();

  f32x4 acc[13];
#pragma unroll
  for (int nt = 0; nt < 13; ++nt) acc[nt] = (f32x4){0.f, 0.f, 0.f, 0.f};

  for (int kc = 0; kc < 16; ++kc) {
    const int cur = kc & 1;
    const ushort_t* wSc = smem + cur * 16384;
    const ushort_t* fhc = smem + 32768 + cur * 6656;
    const ushort_t* flc = smem + 46080 + cur * 6656;
    const int a0 = kc * 32;

    // we/bias for CURRENT chunk (latency hides under fc1 MFMAs)
    float wev[2][4], bias[2];
#pragma unroll
    for (int nt = 0; nt < 2; ++nt) {
      const int a = a0 + nt * 16 + l16;
      bias[nt] = fb1[a];
#pragma unroll
      for (int r = 0; r < 4; ++r) {
        const int l = l0 + wid * 16 + quad * 4 + r;
        wev[nt][r] = we[((size_t)b * NL + l) * NDW + a];
      }
    }

    // issue next chunk's staging (stays in flight across the whole chunk)
    if (kc < 15) stage1(kc + 1, cur ^ 1);

    // ---- fc1 chunk: q[wave's 16 l][32 a] over K=512, A from registers
    f32x4 aq[2][2];
    aq[0][0] = aq[0][1] = aq[1][0] = aq[1][1] = (f32x4){0.f, 0.f, 0.f, 0.f};
#pragma unroll
    for (int cs = 0; cs < 16; ++cs) {
      bf16x8 af = __builtin_bit_cast(bf16x8, hreg[cs]);
#pragma unroll
      for (int nt = 0; nt < 2; ++nt) {
        bf16x8 bw = *(const bf16x8*)&wSc[(nt * 16 + l16) * 512 +
                                         ((cs * 32 + quad * 8) ^ wmask)];
        aq[cs & 1][nt] = __builtin_amdgcn_mfma_f32_16x16x32_bf16(af, bw, aq[cs & 1][nt], 0, 0, 0);
      }
    }
    // q epilogue: bias + we, split to bf16 hi/lo. qh/ql are WAVE-PRIVATE
    // (each wave writes+reads only rows wid*16..wid*16+15) -> no barrier,
    // just drain this wave's ds_writes.
#pragma unroll
    for (int nt = 0; nt < 2; ++nt) {
#pragma unroll
      for (int r = 0; r < 4; ++r) {
        float qv = aq[0][nt][r] + aq[1][nt][r] + bias[nt] + wev[nt][r];
        ushort_t h = f2bf(qv);
        const int row = wid * 16 + quad * 4 + r;
        qh[row * 36 + nt * 16 + l16] = h;
        ql[row * 36 + nt * 16 + l16] = f2bf(qv - bf2f(h));
      }
    }
    WAITLGKM0();
    __builtin_amdgcn_sched_barrier(0);

    // ---- score chunk: 3-pass split-bf16 MFMA
    bf16x8 ah = *(const bf16x8*)&qh[(wid * 16 + l16) * 36 + quad * 8];
    bf16x8 al = *(const bf16x8*)&ql[(wid * 16 + l16) * 36 + quad * 8];
    const int fcol = (quad * 8) ^ (s_f << 3);
#pragma unroll
    for (int nt = 0; nt < 13; ++nt) {
      bf16x8 bh = *(const bf16x8*)&fhc[(nt * 16 + l16) * 32 + fcol];
      bf16x8 bl = *(const bf16x8*)&flc[(nt * 16 + l16) * 32 + fcol];
      acc[nt] = __builtin_amdgcn_mfma_f32_16x16x32_bf16(ah, bh, acc[nt], 0, 0, 0);
      acc[nt] = __builtin_amdgcn_mfma_f32_16x16x32_bf16(al, bh, acc[nt], 0, 0, 0);
      acc[nt] = __builtin_amdgcn_mfma_f32_16x16x32_bf16(ah, bl, acc[nt], 0, 0, 0);
    }

    // chunk end: drain own ds_reads (license buffer reuse) + own gld16s
    // (next chunk's buffer ready), then barrier.
    if (kc < 15) {
      WAITLGKM0();
      WAITVM0();
      BARM();
    }
  }

  // ---- softmax per row; leave normalized attn in acc[][]; write out_attn
  const bool v12 = (l16 < 4);
#pragma unroll
  for (int r = 0; r < 4; ++r) {
    float mx = -1e30f;
#pragma unroll
    for (int nt = 0; nt < 12; ++nt) mx = fmaxf(mx, acc[nt][r]);
    if (v12) mx = fmaxf(mx, acc[12][r]);
#pragma unroll
    for (int off = 1; off < 16; off <<= 1) mx = fmaxf(mx, __shfl_xor(mx, off, 16));
    float ex[13];
    float sum = 0.f;
#pragma unroll
    for (int nt = 0; nt < 12; ++nt) { ex[nt] = __expf(acc[nt][r] - mx); sum += ex[nt]; }
    ex[12] = v12 ? __expf(acc[12][r] - mx) : 0.f;
    sum += ex[12];
#pragma unroll
    for (int off = 1; off < 16; off <<= 1) sum += __shfl_xor(sum, off, 16);
    const float inv = 1.f / sum;
    const int l = l0 + wid * 16 + quad * 4 + r;
    float* ao = out_attn + ((size_t)b * NL + l) * NHW;
#pragma unroll
    for (int nt = 0; nt < 13; ++nt) {
      float av = ex[nt] * inv;
      acc[nt][r] = av;
      int p = nt * 16 + l16;
      if (p < NHW) ao[p] = av;
    }
  }

  __syncthreads();  // full drain: phase-1 LDS dead -> safe to alias

  // ---- phase 2: attn -> pa (bf16, padded to 224), pipelined ctx MFMA.
  auto stage2 = [&](int ac, int s) {
    const int a0c = ac * 32;
    ushort_t* fbb = smem + 14848 + s * 7168;
    // 32 rows x 448B = 14336B = 14 linear wave-issues of 1024B.
#pragma unroll
    for (int ii = 0; ii < 4; ++ii) {
      const int i = ii * 4 + wid;
      if (i < 14) {
        const int byte0 = i * 1024 + lane * 16;
        const unsigned q64 = (unsigned)byte0 >> 6;
        const int row = (int)(q64 / 7u);
        const int colb = (int)(q64 - (unsigned)row * 7u) * 64 + (byte0 & 63);
        const int cu = colb >> 1;
        const int s4 = (row + (row >> 2)) & 3;
        gld16(fbf + ((size_t)b * NDW + a0c + row) * NPK + (cu ^ (s4 << 3)),
              fbb + i * 512 + lane * 8);
      }
    }
  };

#pragma unroll
  for (int r = 0; r < 4; ++r) {
    const int row = wid * 16 + quad * 4 + r;
#pragma unroll
    for (int nt = 0; nt < 13; ++nt) {
      int p = nt * 16 + l16;
      pa[row * 232 + p] = (p < NHW) ? f2bf(acc[nt][r]) : (ushort_t)0;
    }
    pa[row * 232 + 208 + l16] = 0;
  }
  stage2(0, 0);
  __syncthreads();

  for (int ac = 0; ac < 16; ++ac) {
    const int cur = ac & 1;
    const ushort_t* fbc = smem + 14848 + cur * 7168;
    if (ac < 15) stage2(ac + 1, cur ^ 1);

    f32x4 ca[2];
    ca[0] = ca[1] = (f32x4){0.f, 0.f, 0.f, 0.f};
#pragma unroll
    for (int ks = 0; ks < 7; ++ks) {
      bf16x8 af = *(const bf16x8*)&pa[(wid * 16 + l16) * 232 + ks * 32 + quad * 8];
#pragma unroll
      for (int nt = 0; nt < 2; ++nt) {
        bf16x8 bv = *(const bf16x8*)&fbc[(nt * 16 + l16) * 224 +
                                         ((ks * 32 + quad * 8) ^ (s_f << 3))];
        ca[nt] = __builtin_amdgcn_mfma_f32_16x16x32_bf16(af, bv, ca[nt], 0, 0, 0);
      }
    }
#pragma unroll
    for (int nt = 0; nt < 2; ++nt) {
      const int a = ac * 32 + nt * 16 + l16;
#pragma unroll
      for (int r = 0; r < 4; ++r) {
        const int l = l0 + wid * 16 + quad * 4 + r;
        ctx_bf[((size_t)b * NL + l) * NDW + a] = f2bf(ca[nt][r]);
      }
    }
    if (ac < 15) {
      WAITLGKM0();
      WAITVM0();
      BARM();
    }
  }
}

// ---------------------------------------------------------------------------
// K5: fc2 MFMA.  out[c][l] = sum_a w2bf[c][a]*ctx_bf[l][a] + fb2[c] + h + x
// ---------------------------------------------------------------------------
__global__ __launch_bounds__(256, 2) void fc2_mfma(
    const ushort_t* __restrict__ w2bf, const ushort_t* __restrict__ ctx_bf,
    const float* __restrict__ fb2, const ushort_t* __restrict__ hbfT,
    const float* __restrict__ x, float* __restrict__ out0) {
  const int b  = blockIdx.z;
  const int c0 = blockIdx.y * 128;
  const int l0 = blockIdx.x * 128;
  const int tid = threadIdx.x;
  const int wid = tid >> 6;
  const int lane = tid & 63;
  const int wl = wid & 1;   // c sub-tile
  const int wc = wid >> 1;  // l sub-tile
  const int quad = lane >> 4;
  const int l16 = lane & 15;

  __shared__ ushort_t la[128][72];
  __shared__ ushort_t lb[128][72];

  f32x4 acc[4][4];
#pragma unroll
  for (int mt = 0; mt < 4; ++mt)
#pragma unroll
    for (int nt = 0; nt < 4; ++nt) acc[mt][nt] = (f32x4){0.f, 0.f, 0.f, 0.f};

  for (int a0 = 0; a0 < NDW; a0 += 64) {
    __syncthreads();
#pragma unroll
    for (int it = 0; it < 4; ++it) {
      int t = tid + it * 256;
      int r = t >> 3, seg = t & 7;
      *(uint4*)&la[r][seg * 8] = *(const uint4*)(w2bf + (size_t)(c0 + r) * NDW + a0 + seg * 8);
    }
#pragma unroll
    for (int it = 0; it < 4; ++it) {
      int t = tid + it * 256;
      int r = t >> 3, seg = t & 7;
      *(uint4*)&lb[r][seg * 8] =
          *(const uint4*)(ctx_bf + ((size_t)b * NL + l0 + r) * NDW + a0 + seg * 8);
    }
    __syncthreads();
#pragma unroll
    for (int ks = 0; ks < 2; ++ks) {
      bf16x8 af[4];
#pragma unroll
      for (int mt = 0; mt < 4; ++mt)
        af[mt] = *(const bf16x8*)&la[wl * 64 + mt * 16 + l16][ks * 32 + quad * 8];
#pragma unroll
      for (int nt = 0; nt < 4; ++nt) {
        bf16x8 bf = *(const bf16x8*)&lb[wc * 64 + nt * 16 + l16][ks * 32 + quad * 8];
#pragma unroll
        for (int mt = 0; mt < 4; ++mt)
          acc[mt][nt] = __builtin_amdgcn_mfma_f32_16x16x32_bf16(af[mt], bf, acc[mt][nt], 0, 0, 0);
      }
    }
  }

#pragma unroll
  for (int mt = 0; mt < 4; ++mt) {
    const int cb = c0 + wl * 64 + mt * 16 + quad * 4;
    float4 bias4 = *(const float4*)&fb2[cb];
#pragma unroll
    for (int nt = 0; nt < 4; ++nt) {
      const int l = l0 + wc * 64 + nt * 16 + l16;
      ushort4 h4 = *(const ushort4*)&hbfT[((size_t)b * NL + l) * NDW + cb];
      const float bias[4] = {bias4.x, bias4.y, bias4.z, bias4.w};
      const ushort_t hs[4] = {h4.x, h4.y, h4.z, h4.w};
#pragma unroll
      for (int r = 0; r < 4; ++r) {
        size_t idx = ((size_t)b * NDW + cb + r) * NL + l;
        out0[idx] = acc[mt][nt][r] + bias[r] + bf2f(hs[r]) + x[idx];
      }
    }
  }
}

// ---------------------------------------------------------------------------
extern "C" void kernel_launch(void* const* d_in, const int* in_sizes, int n_in,
                              void* d_out, int out_size, void* d_ws, size_t ws_size,
                              hipStream_t stream) {
  const float* x      = (const float*)d_in[0];
  const float* we     = (const float*)d_in[1];
  const float* img    = (const float*)d_in[2];
  const float* conv_v = (const float*)d_in[4];
  const float* conv_g = (const float*)d_in[5];
  const float* conv_b = (const float*)d_in[6];
  const float* fc1_w  = (const float*)d_in[7];
  const float* fc1_b  = (const float*)d_in[8];
  const float* fc2_w  = (const float*)d_in[9];
  const float* fc2_b  = (const float*)d_in[10];

  float* out0     = (float*)d_out;          // (16,512,1024)
  float* out_we   = out0 + 8388608;         // (16,1024,512)
  float* out_img  = out_we + 8388608;       // (16,512,14,14)
  float* out_attn = out_img + 1605632;      // (16,1024,196)

  // Workspace layout (ushort units).
  ushort_t* wsu = (ushort_t*)d_ws;
  ushort_t* wperm = wsu;                    // 2,621,440   [phase A]
  ushort_t* xT    = wsu + 2621440;          // 8,421,376 (16x1028x512) [phase A]
  ushort_t* ctx_b = wsu;                    // 8,388,608   [attn_fused -> fc2; wperm/xT dead]
  ushort_t* hbfT  = wsu + 16777216;         // 8,388,608   [conv -> attn_fused/fc2]
  ushort_t* w1bf  = wsu + 25165824;         // 262,144
  ushort_t* w2bf  = wsu + 25165824 + 262144;  // 262,144
  ushort_t* fThi  = wsu + 25690112;         // 1,703,936
  ushort_t* fTlo  = wsu + 27394048;         // 1,703,936
  ushort_t* fbf   = wsu + 29097984;         // 1,835,008  -> ends 30,932,992

  wnorm_kernel<<<dim3(NCOUT), 256, 0, stream>>>(conv_v, conv_g, wperm);
  xpose_kernel<<<dim3(16, 8, NB), 256, 0, stream>>>(x, xT);
  wcvt_kernel<<<dim3(256), 256, 0, stream>>>(fc1_w, fc2_w, w1bf, w2bf);
  ftrans_kernel<<<dim3(8, NB), 256, 0, stream>>>(img, fThi, fTlo, fbf);

  conv_glu_mfma<<<dim3(64, 4), 512, 0, stream>>>(xT, wperm, conv_b, hbfT);
  attn_fused<<<dim3(16, NB), 256, 0, stream>>>(hbfT, w1bf, fc1_b, we,
                                               fThi, fTlo, fbf, out_attn, ctx_b);
  fc2_mfma<<<dim3(8, 4, NB), 256, 0, stream>>>(w2bf, ctx_b, fc2_b, hbfT, x, out0);

  hipMemcpyAsync(out_we, we, (size_t)8388608 * sizeof(float),
                 hipMemcpyDeviceToDevice, stream);
  hipMemcpyAsync(out_img, img, (size_t)1605632 * sizeof(float),
                 hipMemcpyDeviceToDevice, stream);
}

// Round 9
// 355.962 us; speedup vs baseline: 1.5400x; 1.1002x over previous
//
#include <hip/hip_runtime.h>
#include <math.h>

// Sizes (fixed for this problem)
#define NB   16
#define NCIN 512
#define NL   1024
#define NCOUT 1024
#define NK   5
#define NDW  512
#define NHW  196
#define NP   208   // HW padded to 13 n-tiles of 16
#define NPK  224   // HW padded to 7 k-chunks of 32
#define NLG  1028  // NL + 4 zero guard rows at the front of each batch (for conv taps)

typedef unsigned short ushort_t;
typedef unsigned int uint_t;
typedef __attribute__((ext_vector_type(8))) short bf16x8;
typedef __attribute__((ext_vector_type(4))) float f32x4;

static __device__ __forceinline__ ushort_t f2bf(float f) {
  uint_t u = __builtin_bit_cast(uint_t, f);
  u += 0x7fff + ((u >> 16) & 1);  // round-to-nearest-even
  return (ushort_t)(u >> 16);
}
static __device__ __forceinline__ float bf2f(ushort_t u) {
  uint_t v = ((uint_t)u) << 16;
  return __builtin_bit_cast(float, v);
}

// raw barrier / counted waits (avoid __syncthreads' vmcnt(0) drain)
#define BARM()      asm volatile("s_barrier" ::: "memory")
#define WAITVM8()   asm volatile("s_waitcnt vmcnt(8)" ::: "memory")
#define WAITVM0()   asm volatile("s_waitcnt vmcnt(0)" ::: "memory")
#define WAITLGKM0() asm volatile("s_waitcnt lgkmcnt(0)" ::: "memory")

static __device__ __forceinline__ void gld16(const ushort_t* g, ushort_t* l) {
  __builtin_amdgcn_global_load_lds(
      (const __attribute__((address_space(1))) unsigned int*)g,
      (__attribute__((address_space(3))) unsigned int*)l, 16, 0, 0);
}

// ---------------------------------------------------------------------------
// K1: weight norm -> permuted bf16 weights (conv kernel's interleaved order).
// Also folds in the fc1_w/fc2_w bf16 conversion (blocks 0..255) to drop a
// dispatch.
// ---------------------------------------------------------------------------
__global__ __launch_bounds__(256) void wnorm_kernel(
    const float* __restrict__ v, const float* __restrict__ g,
    ushort_t* __restrict__ wperm,
    const float* __restrict__ w1, const float* __restrict__ w2,
    ushort_t* __restrict__ w1bf, ushort_t* __restrict__ w2bf) {
  const int o = blockIdx.x;
  const float* vr = v + (size_t)o * (NCIN * NK);
  float s = 0.f;
  for (int j = threadIdx.x; j < NCIN * NK; j += 256) {
    float t = vr[j];
    s += t * t;
  }
  for (int off = 32; off; off >>= 1) s += __shfl_down(s, off, 64);
  __shared__ float red[4];
  __shared__ float scale_s;
  const int wid = threadIdx.x >> 6;
  if ((threadIdx.x & 63) == 0) red[wid] = s;
  __syncthreads();
  if (threadIdx.x == 0) {
    float tot = red[0] + red[1] + red[2] + red[3];
    scale_s = g[o] / sqrtf(tot);
  }
  __syncthreads();
  const float scale = scale_s;
  const int isB = (o >= NDW) ? 1 : 0;
  const int c = o - isB * NDW;
  const int j = (c >> 5) * 64 + isB * 32 + (c & 31);
#pragma unroll
  for (int dk = 0; dk < NK; ++dk) {
    for (int ci = threadIdx.x; ci < NCIN; ci += 256) {
      wperm[((size_t)dk * NCOUT + j) * NCIN + ci] = f2bf(vr[ci * NK + dk] * scale);
    }
  }
  // folded wcvt: blocks 0..255 also convert fc1_w/fc2_w (262144 elems each)
  if (o < 256) {
    const int i = (o * 256 + threadIdx.x) * 4;
    {
      float4 vv = *(const float4*)&w1[i];
      ushort4 oo; oo.x = f2bf(vv.x); oo.y = f2bf(vv.y); oo.z = f2bf(vv.z); oo.w = f2bf(vv.w);
      *(ushort4*)&w1bf[i] = oo;
    }
    {
      float4 vv = *(const float4*)&w2[i];
      ushort4 oo; oo.x = f2bf(vv.x); oo.y = f2bf(vv.y); oo.z = f2bf(vv.z); oo.w = f2bf(vv.w);
      *(ushort4*)&w2bf[i] = oo;
    }
  }
}

// ---------------------------------------------------------------------------
// K2a: transpose + bf16 convert:  xT[b][l+4][ci] = bf16(x[b][ci][l])
// ---------------------------------------------------------------------------
__global__ __launch_bounds__(256) void xpose_kernel(
    const float* __restrict__ x, ushort_t* __restrict__ xT) {
  const int b = blockIdx.z;
  const int ci0 = blockIdx.y * 64;
  const int l0 = blockIdx.x * 64;
  const int tid = threadIdx.x;
  __shared__ float t[64][65];
  const float* xb = x + ((size_t)b * NCIN + ci0) * NL + l0;
#pragma unroll
  for (int r = 0; r < 4; ++r) {
    int row = r * 16 + (tid >> 4);
    int col = (tid & 15) * 4;
    float4 v = *(const float4*)&xb[(size_t)row * NL + col];
    t[row][col + 0] = v.x; t[row][col + 1] = v.y;
    t[row][col + 2] = v.z; t[row][col + 3] = v.w;
  }
  __syncthreads();
  ushort_t* xo = xT + ((size_t)b * NLG + l0 + 4) * NCIN + ci0;
#pragma unroll
  for (int r = 0; r < 4; ++r) {
    int lrow = r * 16 + (tid >> 4);
    int cic = (tid & 15) * 4;
    ushort4 o4;
    o4.x = f2bf(t[cic + 0][lrow]);
    o4.y = f2bf(t[cic + 1][lrow]);
    o4.z = f2bf(t[cic + 2][lrow]);
    o4.w = f2bf(t[cic + 3][lrow]);
    *(ushort4*)&xo[(size_t)lrow * NCIN + cic] = o4;
  }
  // zero the 4 guard rows for this (b, ci-slice)
  if (blockIdx.x == 0) {
    for (int i = tid; i < 4 * 64; i += 256) {
      int rr = i >> 6, cc = i & 63;
      xT[((size_t)b * NLG + rr) * NCIN + ci0 + cc] = 0;
    }
  }
}

// ---------------------------------------------------------------------------
// K-prep: feat transforms (512 threads: halves per-thread serial work; grid
// was only 128 blocks on 256 CUs, latency-bound).
// ---------------------------------------------------------------------------
__global__ __launch_bounds__(512) void ftrans_kernel(
    const float* __restrict__ feat, ushort_t* __restrict__ fThi,
    ushort_t* __restrict__ fTlo, ushort_t* __restrict__ fbf) {
  const int b = blockIdx.y;
  const int a0 = blockIdx.x * 64;
  const int tid = threadIdx.x;  // 0..511
  __shared__ float t[64][200];

  const float* fb_ = feat + ((size_t)b * NDW + a0) * NHW;
#pragma unroll
  for (int pp = 0; pp < 8; ++pp) {
    int row = pp * 8 + (tid >> 6);
#pragma unroll
    for (int cc = 0; cc < 4; ++cc) {
      int col = cc * 64 + (tid & 63);
      if (col < NHW) t[row][col] = fb_[(size_t)row * NHW + col];
    }
  }
  __syncthreads();

  // fT writes: 208 p-rows x 64 a (ushort2 per thread per pass)
  for (int pp = 0; pp < 13; ++pp) {
    int p = pp * 16 + (tid >> 5);
    int j = (tid & 31) * 2;
    ushort2 hi2, lo2;
#pragma unroll
    for (int k = 0; k < 2; ++k) {
      float v = (p < NHW) ? t[j + k][p] : 0.f;
      ushort_t h = f2bf(v);
      float lof = v - bf2f(h);
      ((ushort_t*)&hi2)[k] = h;
      ((ushort_t*)&lo2)[k] = f2bf(lof);
    }
    size_t base = ((size_t)b * NP + p) * NDW + a0 + j;
    *(ushort2*)&fThi[base] = hi2;
    *(ushort2*)&fTlo[base] = lo2;
  }

  // fbf writes: 64 a-rows x 224 p
#pragma unroll
  for (int cc = 0; cc < 4; ++cc) {
    int col = cc * 64 + (tid & 63);
    if (col < NPK) {
#pragma unroll
      for (int rr = 0; rr < 8; ++rr) {
        int al = rr * 8 + (tid >> 6);
        float v = (col < NHW) ? t[al][col] : 0.f;
        fbf[((size_t)b * NDW + a0 + al) * NPK + col] = f2bf(v);
      }
    }
  }
}

// ---------------------------------------------------------------------------
// K2b: conv1d + bias + GLU via bf16 MFMA implicit GEMM — 256x256 phase-split.
// (round-6 verified: race-fixed with lgkmcnt(0) before the overwrite barrier)
// ---------------------------------------------------------------------------
__global__ __launch_bounds__(512, 2) void conv_glu_mfma(
    const ushort_t* __restrict__ xT, const ushort_t* __restrict__ wperm,
    const float* __restrict__ conv_b, ushort_t* __restrict__ hbfT) {
  const int bb = blockIdx.x >> 2;
  const int l0 = (blockIdx.x & 3) * 256;
  const int by = blockIdx.y;
  const int tid = threadIdx.x;
  const int wid = tid >> 6;
  const int lane = tid & 63;
  const int wm = wid >> 2;   // M half (0,1)
  const int wn = wid & 3;    // N quarter (0..3)
  const int quad = lane >> 4;
  const int l16 = lane & 15;
  const int sw = (l16 & 7) << 3;                        // read-side XOR (ushort units)
  const int csrc = ((lane & 7) ^ (lane >> 3)) << 3;     // staging source col (ushort units)

  __shared__ ushort_t sA[2][256][64];
  __shared__ ushort_t sB[2][256][64];

  f32x4 acc[8][4];
#pragma unroll
  for (int mt = 0; mt < 8; ++mt)
#pragma unroll
    for (int nt = 0; nt < 4; ++nt) acc[mt][nt] = (f32x4){0.f, 0.f, 0.f, 0.f};

  const ushort_t* gAbase = xT + (size_t)(bb * NLG + l0) * NCIN;
  const int r0 = wid * 8 + (lane >> 3);
  ushort_t* lA0 = &sA[0][0][0] + (wid * 64 + lane) * 8;
  ushort_t* lB0 = &sB[0][0][0] + (wid * 64 + lane) * 8;

  auto stage = [&](int tt, int s) {
    const int dk = tt >> 3;
    const int ci0 = (tt & 7) << 6;
    const ushort_t* gA = gAbase + (size_t)dk * NCIN + ci0 + csrc;
    const ushort_t* gB = wperm + ((size_t)dk * NCOUT + by * 256) * NCIN + ci0 + csrc;
    ushort_t* lA = lA0 + s * (256 * 64);
    ushort_t* lB = lB0 + s * (256 * 64);
#pragma unroll
    for (int c = 0; c < 4; ++c) {
      gld16(gA + (size_t)(r0 + c * 64) * NCIN, lA + c * 4096);
      gld16(gB + (size_t)(r0 + c * 64) * NCIN, lB + c * 4096);
    }
  };

  stage(0, 0);
  stage(1, 1);
  WAITVM8();
  BARM();

  for (int t = 0; t < 40; ++t) {
    const int s = t & 1;
    bf16x8 af[4][2], bfr[4][2];

    // ---- phase 0: read A(mth=0) + B(nt 0,1); MFMA quadrant (0,0)
#pragma unroll
    for (int mt = 0; mt < 4; ++mt)
#pragma unroll
      for (int ks = 0; ks < 2; ++ks)
        af[mt][ks] = *(const bf16x8*)&sA[s][wm * 128 + mt * 16 + l16]
                                        [(ks * 32 + quad * 8) ^ sw];
#pragma unroll
    for (int nt = 0; nt < 2; ++nt)
#pragma unroll
      for (int ks = 0; ks < 2; ++ks)
        bfr[nt][ks] = *(const bf16x8*)&sB[s][wn * 64 + nt * 16 + l16]
                                         [(ks * 32 + quad * 8) ^ sw];
    BARM();
    __builtin_amdgcn_s_setprio(1);
#pragma unroll
    for (int ks = 0; ks < 2; ++ks)
#pragma unroll
      for (int nt = 0; nt < 2; ++nt)
#pragma unroll
        for (int mt = 0; mt < 4; ++mt)
          acc[mt][nt] = __builtin_amdgcn_mfma_f32_16x16x32_bf16(
              af[mt][ks], bfr[nt][ks], acc[mt][nt], 0, 0, 0);
    __builtin_amdgcn_s_setprio(0);
    BARM();

    // ---- phase 1: read B(nt 2,3); MFMA quadrant (0,1)
#pragma unroll
    for (int nt = 2; nt < 4; ++nt)
#pragma unroll
      for (int ks = 0; ks < 2; ++ks)
        bfr[nt][ks] = *(const bf16x8*)&sB[s][wn * 64 + nt * 16 + l16]
                                         [(ks * 32 + quad * 8) ^ sw];
    BARM();
    __builtin_amdgcn_s_setprio(1);
#pragma unroll
    for (int ks = 0; ks < 2; ++ks)
#pragma unroll
      for (int nt = 2; nt < 4; ++nt)
#pragma unroll
        for (int mt = 0; mt < 4; ++mt)
          acc[mt][nt] = __builtin_amdgcn_mfma_f32_16x16x32_bf16(
              af[mt][ks], bfr[nt][ks], acc[mt][nt], 0, 0, 0);
    __builtin_amdgcn_s_setprio(0);
    BARM();

    // ---- phase 2: read A(mth=1); MFMA quadrant (1,0)
#pragma unroll
    for (int mt = 0; mt < 4; ++mt)
#pragma unroll
      for (int ks = 0; ks < 2; ++ks)
        af[mt][ks] = *(const bf16x8*)&sA[s][wm * 128 + (4 + mt) * 16 + l16]
                                        [(ks * 32 + quad * 8) ^ sw];
    BARM();
    __builtin_amdgcn_s_setprio(1);
#pragma unroll
    for (int ks = 0; ks < 2; ++ks)
#pragma unroll
      for (int nt = 0; nt < 2; ++nt)
#pragma unroll
        for (int mt = 0; mt < 4; ++mt)
          acc[4 + mt][nt] = __builtin_amdgcn_mfma_f32_16x16x32_bf16(
              af[mt][ks], bfr[nt][ks], acc[4 + mt][nt], 0, 0, 0);
    __builtin_amdgcn_s_setprio(0);
    // RACE FIX: drain this wave's LDS reads of slot s BEFORE signalling the
    // barrier that licenses the phase-3 overwrite of slot s.
    WAITLGKM0();
    BARM();

    // ---- phase 3: issue prefetch of tile t+2 into slot s, MFMA (1,1)
    if (t < 38) stage(t + 2, s);
    __builtin_amdgcn_s_setprio(1);
#pragma unroll
    for (int ks = 0; ks < 2; ++ks)
#pragma unroll
      for (int nt = 2; nt < 4; ++nt)
#pragma unroll
        for (int mt = 0; mt < 4; ++mt)
          acc[4 + mt][nt] = __builtin_amdgcn_mfma_f32_16x16x32_bf16(
              af[mt][ks], bfr[nt][ks], acc[4 + mt][nt], 0, 0, 0);
    __builtin_amdgcn_s_setprio(0);

    if (t < 39) {
      if (t < 38) { WAITVM8(); } else { WAITVM0(); }
      BARM();
    }
  }

  // epilogue: GLU, write hbfT[b][l][c] (c < 512)
#pragma unroll
  for (int nt = 0; nt < 2; ++nt) {
    const int c = by * 128 + wn * 32 + nt * 16 + l16;
    const float ba = conv_b[c];
    const float bg = conv_b[c + NDW];
#pragma unroll
    for (int mt = 0; mt < 8; ++mt) {
      const int lg = l0 + wm * 128 + mt * 16 + quad * 4;
      ushort_t* ho = hbfT + ((size_t)bb * NL + lg) * NDW + c;
#pragma unroll
      for (int r = 0; r < 4; ++r) {
        float aa = acc[mt][nt][r] + ba;
        float gg = acc[mt][nt + 2][r] + bg;
        float hv = aa * (1.f / (1.f + __expf(-gg)));
        ho[(size_t)r * NDW] = f2bf(hv);
      }
    }
  }
}

// ---------------------------------------------------------------------------
// K3: FUSED fc1 + score + softmax + ctx  (v4: global_load_lds pipeline).
// (round-8 verified: 391.6 total, attn out of top-5, absmax 0.046875)
// ---------------------------------------------------------------------------
__global__ __launch_bounds__(256, 2) void attn_fused(
    const ushort_t* __restrict__ hbfT, const ushort_t* __restrict__ w1bf,
    const float* __restrict__ fb1, const float* __restrict__ we,
    const ushort_t* __restrict__ fThi, const ushort_t* __restrict__ fTlo,
    const ushort_t* __restrict__ fbf, float* __restrict__ out_attn,
    ushort_t* __restrict__ ctx_bf) {
  const int b  = blockIdx.y;
  const int l0 = blockIdx.x * 64;
  const int tid = threadIdx.x;
  const int wid = tid >> 6;
  const int lane = tid & 63;
  const int quad = lane >> 4;
  const int l16 = lane & 15;
  const int s_f = ((l16 & 3) + (l16 >> 2)) & 3;  // fh/fl/fbf read swizzle slot
  const int wmask = (l16 & 7) << 3;              // wS read swizzle (ushort units)

  // LDS layout (ushort units), total 64000 u = 125 KiB:
  //   wS[2] @0     2 x [32][512] = 32768
  //   fh[2] @32768 2 x [208][32] = 13312
  //   fl[2] @46080 2 x [208][32] = 13312
  //   qh    @59392 [64][36] = 2304
  //   ql    @61696 [64][36] = 2304
  // phase 2 aliases: pa @0 [64][232]=14848; fb[2] @14848 2 x [32][224]=14336
  __shared__ ushort_t smem[64000];
  ushort_t* qh = smem + 59392;
  ushort_t* ql = smem + 61696;
  ushort_t* pa = smem;

  // stage chunk kc's w1 + fThi/fTlo slab into LDS buffer s via gld16.
  auto stage1 = [&](int kc, int s) {
    const int a0 = kc * 32;
    ushort_t* wSb = smem + s * 16384;
    ushort_t* fhb = smem + 32768 + s * 6656;
    ushort_t* flb = smem + 46080 + s * 6656;
    // wS: 32 rows x 1024B, one wave-issue per row; wave wid does rows wid+4k.
#pragma unroll
    for (int rr = 0; rr < 8; ++rr) {
      const int r = rr * 4 + wid;
      gld16(w1bf + (size_t)(a0 + r) * NDW + ((lane * 8) ^ ((r & 7) << 3)),
            wSb + r * 512 + lane * 8);
    }
    // fh/fl: 13 issues x 16 rows x 64B each.
#pragma unroll
    for (int ii = 0; ii < 4; ++ii) {
      const int i = ii * 4 + wid;
      if (i < 13) {
        const int row = i * 16 + (lane >> 2);
        const int s4 = (row + (row >> 2)) & 3;
        const size_t gsrc =
            ((size_t)b * NP + row) * NDW + a0 + (((lane & 3) * 8) ^ (s4 << 3));
        gld16(fThi + gsrc, fhb + i * 512 + lane * 8);
        gld16(fTlo + gsrc, flb + i * 512 + lane * 8);
      }
    }
  };

  // h tile in registers: this wave's 16 l-rows x 512 c as A-fragments.
  uint4 hreg[16];
  {
    const ushort_t* hrow =
        hbfT + ((size_t)b * NL + l0 + wid * 16 + l16) * NDW + quad * 8;
#pragma unroll
    for (int cs = 0; cs < 16; ++cs)
      hreg[cs] = *(const uint4*)(hrow + cs * 32);
  }

  stage1(0, 0);
  __syncthreads();

  f32x4 acc[13];
#pragma unroll
  for (int nt = 0; nt < 13; ++nt) acc[nt] = (f32x4){0.f, 0.f, 0.f, 0.f};

  for (int kc = 0; kc < 16; ++kc) {
    const int cur = kc & 1;
    const ushort_t* wSc = smem + cur * 16384;
    const ushort_t* fhc = smem + 32768 + cur * 6656;
    const ushort_t* flc = smem + 46080 + cur * 6656;
    const int a0 = kc * 32;

    // we/bias for CURRENT chunk (latency hides under fc1 MFMAs)
    float wev[2][4], bias[2];
#pragma unroll
    for (int nt = 0; nt < 2; ++nt) {
      const int a = a0 + nt * 16 + l16;
      bias[nt] = fb1[a];
#pragma unroll
      for (int r = 0; r < 4; ++r) {
        const int l = l0 + wid * 16 + quad * 4 + r;
        wev[nt][r] = we[((size_t)b * NL + l) * NDW + a];
      }
    }

    // issue next chunk's staging (stays in flight across the whole chunk)
    if (kc < 15) stage1(kc + 1, cur ^ 1);

    // ---- fc1 chunk: q[wave's 16 l][32 a] over K=512, A from registers
    f32x4 aq[2][2];
    aq[0][0] = aq[0][1] = aq[1][0] = aq[1][1] = (f32x4){0.f, 0.f, 0.f, 0.f};
#pragma unroll
    for (int cs = 0; cs < 16; ++cs) {
      bf16x8 af = __builtin_bit_cast(bf16x8, hreg[cs]);
#pragma unroll
      for (int nt = 0; nt < 2; ++nt) {
        bf16x8 bw = *(const bf16x8*)&wSc[(nt * 16 + l16) * 512 +
                                         ((cs * 32 + quad * 8) ^ wmask)];
        aq[cs & 1][nt] = __builtin_amdgcn_mfma_f32_16x16x32_bf16(af, bw, aq[cs & 1][nt], 0, 0, 0);
      }
    }
    // q epilogue: bias + we, split to bf16 hi/lo. qh/ql are WAVE-PRIVATE
    // (each wave writes+reads only rows wid*16..wid*16+15) -> no barrier,
    // just drain this wave's ds_writes.
#pragma unroll
    for (int nt = 0; nt < 2; ++nt) {
#pragma unroll
      for (int r = 0; r < 4; ++r) {
        float qv = aq[0][nt][r] + aq[1][nt][r] + bias[nt] + wev[nt][r];
        ushort_t h = f2bf(qv);
        const int row = wid * 16 + quad * 4 + r;
        qh[row * 36 + nt * 16 + l16] = h;
        ql[row * 36 + nt * 16 + l16] = f2bf(qv - bf2f(h));
      }
    }
    WAITLGKM0();
    __builtin_amdgcn_sched_barrier(0);

    // ---- score chunk: 3-pass split-bf16 MFMA
    bf16x8 ah = *(const bf16x8*)&qh[(wid * 16 + l16) * 36 + quad * 8];
    bf16x8 al = *(const bf16x8*)&ql[(wid * 16 + l16) * 36 + quad * 8];
    const int fcol = (quad * 8) ^ (s_f << 3);
#pragma unroll
    for (int nt = 0; nt < 13; ++nt) {
      bf16x8 bh = *(const bf16x8*)&fhc[(nt * 16 + l16) * 32 + fcol];
      bf16x8 bl = *(const bf16x8*)&flc[(nt * 16 + l16) * 32 + fcol];
      acc[nt] = __builtin_amdgcn_mfma_f32_16x16x32_bf16(ah, bh, acc[nt], 0, 0, 0);
      acc[nt] = __builtin_amdgcn_mfma_f32_16x16x32_bf16(al, bh, acc[nt], 0, 0, 0);
      acc[nt] = __builtin_amdgcn_mfma_f32_16x16x32_bf16(ah, bl, acc[nt], 0, 0, 0);
    }

    // chunk end: drain own ds_reads (license buffer reuse) + own gld16s
    // (next chunk's buffer ready), then barrier.
    if (kc < 15) {
      WAITLGKM0();
      WAITVM0();
      BARM();
    }
  }

  // ---- softmax per row; leave normalized attn in acc[][]; write out_attn
  const bool v12 = (l16 < 4);
#pragma unroll
  for (int r = 0; r < 4; ++r) {
    float mx = -1e30f;
#pragma unroll
    for (int nt = 0; nt < 12; ++nt) mx = fmaxf(mx, acc[nt][r]);
    if (v12) mx = fmaxf(mx, acc[12][r]);
#pragma unroll
    for (int off = 1; off < 16; off <<= 1) mx = fmaxf(mx, __shfl_xor(mx, off, 16));
    float ex[13];
    float sum = 0.f;
#pragma unroll
    for (int nt = 0; nt < 12; ++nt) { ex[nt] = __expf(acc[nt][r] - mx); sum += ex[nt]; }
    ex[12] = v12 ? __expf(acc[12][r] - mx) : 0.f;
    sum += ex[12];
#pragma unroll
    for (int off = 1; off < 16; off <<= 1) sum += __shfl_xor(sum, off, 16);
    const float inv = 1.f / sum;
    const int l = l0 + wid * 16 + quad * 4 + r;
    float* ao = out_attn + ((size_t)b * NL + l) * NHW;
#pragma unroll
    for (int nt = 0; nt < 13; ++nt) {
      float av = ex[nt] * inv;
      acc[nt][r] = av;
      int p = nt * 16 + l16;
      if (p < NHW) ao[p] = av;
    }
  }

  __syncthreads();  // full drain: phase-1 LDS dead -> safe to alias

  // ---- phase 2: attn -> pa (bf16, padded to 224), pipelined ctx MFMA.
  auto stage2 = [&](int ac, int s) {
    const int a0c = ac * 32;
    ushort_t* fbb = smem + 14848 + s * 7168;
    // 32 rows x 448B = 14336B = 14 linear wave-issues of 1024B.
#pragma unroll
    for (int ii = 0; ii < 4; ++ii) {
      const int i = ii * 4 + wid;
      if (i < 14) {
        const int byte0 = i * 1024 + lane * 16;
        const unsigned q64 = (unsigned)byte0 >> 6;
        const int row = (int)(q64 / 7u);
        const int colb = (int)(q64 - (unsigned)row * 7u) * 64 + (byte0 & 63);
        const int cu = colb >> 1;
        const int s4 = (row + (row >> 2)) & 3;
        gld16(fbf + ((size_t)b * NDW + a0c + row) * NPK + (cu ^ (s4 << 3)),
              fbb + i * 512 + lane * 8);
      }
    }
  };

#pragma unroll
  for (int r = 0; r < 4; ++r) {
    const int row = wid * 16 + quad * 4 + r;
#pragma unroll
    for (int nt = 0; nt < 13; ++nt) {
      int p = nt * 16 + l16;
      pa[row * 232 + p] = (p < NHW) ? f2bf(acc[nt][r]) : (ushort_t)0;
    }
    pa[row * 232 + 208 + l16] = 0;
  }
  stage2(0, 0);
  __syncthreads();

  for (int ac = 0; ac < 16; ++ac) {
    const int cur = ac & 1;
    const ushort_t* fbc = smem + 14848 + cur * 7168;
    if (ac < 15) stage2(ac + 1, cur ^ 1);

    f32x4 ca[2];
    ca[0] = ca[1] = (f32x4){0.f, 0.f, 0.f, 0.f};
#pragma unroll
    for (int ks = 0; ks < 7; ++ks) {
      bf16x8 af = *(const bf16x8*)&pa[(wid * 16 + l16) * 232 + ks * 32 + quad * 8];
#pragma unroll
      for (int nt = 0; nt < 2; ++nt) {
        bf16x8 bv = *(const bf16x8*)&fbc[(nt * 16 + l16) * 224 +
                                         ((ks * 32 + quad * 8) ^ (s_f << 3))];
        ca[nt] = __builtin_amdgcn_mfma_f32_16x16x32_bf16(af, bv, ca[nt], 0, 0, 0);
      }
    }
#pragma unroll
    for (int nt = 0; nt < 2; ++nt) {
      const int a = ac * 32 + nt * 16 + l16;
#pragma unroll
      for (int r = 0; r < 4; ++r) {
        const int l = l0 + wid * 16 + quad * 4 + r;
        ctx_bf[((size_t)b * NL + l) * NDW + a] = f2bf(ca[nt][r]);
      }
    }
    if (ac < 15) {
      WAITLGKM0();
      WAITVM0();
      BARM();
    }
  }
}

// ---------------------------------------------------------------------------
// K5: fc2 MFMA (v2: conv-style gld16 pipeline).
// out[c][l] = sum_a w2bf[c][a]*ctx_bf[l][a] + fb2[c] + h + x.
// Replaces the 2-barrier register-staged structure (vmcnt(0) drains, 8
// short K-tiles -> stall-dominated) with the conv kernel's verified
// schedule: gld16 staging with pre-swizzled sources + XOR read swizzle,
// double-buffered, t+2 prefetch, counted vmcnt(8), lgkm-drained barriers.
// ---------------------------------------------------------------------------
__global__ __launch_bounds__(256, 2) void fc2_mfma(
    const ushort_t* __restrict__ w2bf, const ushort_t* __restrict__ ctx_bf,
    const float* __restrict__ fb2, const ushort_t* __restrict__ hbfT,
    const float* __restrict__ x, float* __restrict__ out0) {
  const int b  = blockIdx.z;
  const int c0 = blockIdx.y * 128;
  const int l0 = blockIdx.x * 128;
  const int tid = threadIdx.x;
  const int wid = tid >> 6;
  const int lane = tid & 63;
  const int wl = wid & 1;   // c sub-tile
  const int wc = wid >> 1;  // l sub-tile
  const int quad = lane >> 4;
  const int l16 = lane & 15;
  const int sw = (l16 & 7) << 3;                     // read-side XOR (ushort units)
  const int csrc = ((lane & 7) ^ (lane >> 3)) << 3;  // staging source col

  __shared__ ushort_t sA[2][128][64];
  __shared__ ushort_t sB[2][128][64];

  f32x4 acc[4][4];
#pragma unroll
  for (int mt = 0; mt < 4; ++mt)
#pragma unroll
    for (int nt = 0; nt < 4; ++nt) acc[mt][nt] = (f32x4){0.f, 0.f, 0.f, 0.f};

  const ushort_t* gA = w2bf + (size_t)c0 * NDW;               // rows c
  const ushort_t* gB = ctx_bf + ((size_t)b * NL + l0) * NDW;  // rows l
  const int r0 = wid * 8 + (lane >> 3);
  ushort_t* lA0 = &sA[0][0][0] + wid * 512 + lane * 8;
  ushort_t* lB0 = &sB[0][0][0] + wid * 512 + lane * 8;

  auto stage = [&](int t, int s) {
    const int a0 = t * 64;
    ushort_t* lA = lA0 + s * (128 * 64);
    ushort_t* lB = lB0 + s * (128 * 64);
#pragma unroll
    for (int c = 0; c < 4; ++c) {
      gld16(gA + (size_t)(r0 + c * 32) * NDW + a0 + csrc, lA + c * 2048);
      gld16(gB + (size_t)(r0 + c * 32) * NDW + a0 + csrc, lB + c * 2048);
    }
  };

  stage(0, 0);
  stage(1, 1);
  WAITVM8();
  BARM();

  for (int t = 0; t < 8; ++t) {
    const int s = t & 1;
    bf16x8 af[4][2], bfr[4][2];
#pragma unroll
    for (int mt = 0; mt < 4; ++mt)
#pragma unroll
      for (int ks = 0; ks < 2; ++ks)
        af[mt][ks] = *(const bf16x8*)&sA[s][wl * 64 + mt * 16 + l16]
                                        [(ks * 32 + quad * 8) ^ sw];
#pragma unroll
    for (int nt = 0; nt < 4; ++nt)
#pragma unroll
      for (int ks = 0; ks < 2; ++ks)
        bfr[nt][ks] = *(const bf16x8*)&sB[s][wc * 64 + nt * 16 + l16]
                                         [(ks * 32 + quad * 8) ^ sw];
    // drain own ds_reads, then barrier: all waves done reading slot s ->
    // safe to overwrite it with the t+2 prefetch.
    WAITLGKM0();
    BARM();
    if (t < 6) stage(t + 2, s);
    __builtin_amdgcn_s_setprio(1);
#pragma unroll
    for (int ks = 0; ks < 2; ++ks)
#pragma unroll
      for (int nt = 0; nt < 4; ++nt)
#pragma unroll
        for (int mt = 0; mt < 4; ++mt)
          acc[mt][nt] = __builtin_amdgcn_mfma_f32_16x16x32_bf16(
              af[mt][ks], bfr[nt][ks], acc[mt][nt], 0, 0, 0);
    __builtin_amdgcn_s_setprio(0);
    if (t < 7) {
      if (t < 6) { WAITVM8(); } else { WAITVM0(); }
      BARM();
    }
  }

  // epilogue: row = c, col = l
#pragma unroll
  for (int mt = 0; mt < 4; ++mt) {
    const int cb = c0 + wl * 64 + mt * 16 + quad * 4;
    float4 bias4 = *(const float4*)&fb2[cb];
#pragma unroll
    for (int nt = 0; nt < 4; ++nt) {
      const int l = l0 + wc * 64 + nt * 16 + l16;
      ushort4 h4 = *(const ushort4*)&hbfT[((size_t)b * NL + l) * NDW + cb];
      const float bias[4] = {bias4.x, bias4.y, bias4.z, bias4.w};
      const ushort_t hs[4] = {h4.x, h4.y, h4.z, h4.w};
#pragma unroll
      for (int r = 0; r < 4; ++r) {
        size_t idx = ((size_t)b * NDW + cb + r) * NL + l;
        out0[idx] = acc[mt][nt][r] + bias[r] + bf2f(hs[r]) + x[idx];
      }
    }
  }
}

// ---------------------------------------------------------------------------
extern "C" void kernel_launch(void* const* d_in, const int* in_sizes, int n_in,
                              void* d_out, int out_size, void* d_ws, size_t ws_size,
                              hipStream_t stream) {
  const float* x      = (const float*)d_in[0];
  const float* we     = (const float*)d_in[1];
  const float* img    = (const float*)d_in[2];
  const float* conv_v = (const float*)d_in[4];
  const float* conv_g = (const float*)d_in[5];
  const float* conv_b = (const float*)d_in[6];
  const float* fc1_w  = (const float*)d_in[7];
  const float* fc1_b  = (const float*)d_in[8];
  const float* fc2_w  = (const float*)d_in[9];
  const float* fc2_b  = (const float*)d_in[10];

  float* out0     = (float*)d_out;          // (16,512,1024)
  float* out_we   = out0 + 8388608;         // (16,1024,512)
  float* out_img  = out_we + 8388608;       // (16,512,14,14)
  float* out_attn = out_img + 1605632;      // (16,1024,196)

  // Workspace layout (ushort units).
  ushort_t* wsu = (ushort_t*)d_ws;
  ushort_t* wperm = wsu;                    // 2,621,440   [phase A]
  ushort_t* xT    = wsu + 2621440;          // 8,421,376 (16x1028x512) [phase A]
  ushort_t* ctx_b = wsu;                    // 8,388,608   [attn_fused -> fc2; wperm/xT dead]
  ushort_t* hbfT  = wsu + 16777216;         // 8,388,608   [conv -> attn_fused/fc2]
  ushort_t* w1bf  = wsu + 25165824;         // 262,144
  ushort_t* w2bf  = wsu + 25165824 + 262144;  // 262,144
  ushort_t* fThi  = wsu + 25690112;         // 1,703,936
  ushort_t* fTlo  = wsu + 27394048;         // 1,703,936
  ushort_t* fbf   = wsu + 29097984;         // 1,835,008  -> ends 30,932,992

  wnorm_kernel<<<dim3(NCOUT), 256, 0, stream>>>(conv_v, conv_g, wperm,
                                                fc1_w, fc2_w, w1bf, w2bf);
  xpose_kernel<<<dim3(16, 8, NB), 256, 0, stream>>>(x, xT);
  ftrans_kernel<<<dim3(8, NB), 512, 0, stream>>>(img, fThi, fTlo, fbf);

  conv_glu_mfma<<<dim3(64, 4), 512, 0, stream>>>(xT, wperm, conv_b, hbfT);
  attn_fused<<<dim3(16, NB), 256, 0, stream>>>(hbfT, w1bf, fc1_b, we,
                                               fThi, fTlo, fbf, out_attn, ctx_b);
  fc2_mfma<<<dim3(8, 4, NB), 256, 0, stream>>>(w2bf, ctx_b, fc2_b, hbfT, x, out0);

  hipMemcpyAsync(out_we, we, (size_t)8388608 * sizeof(float),
                 hipMemcpyDeviceToDevice, stream);
  hipMemcpyAsync(out_img, img, (size_t)1605632 * sizeof(float),
                 hipMemcpyDeviceToDevice, stream);
}